// Round 13
// baseline (193.698 us; speedup 1.0000x reference)
//
#include <hip/hip_runtime.h>
#include <hip/hip_bf16.h>
#include <hip/hip_fp8.h>

#define N_NODES 100000
#define N_EDGES 1600000
#define D 64
#define BN_EPS 1e-5f
#define NBKT 391   // buckets of 256 nodes: ceil(100000/256)
#define EPB 1024   // edges per block in pass A/B
#define EB 1563    // ceil(N_EDGES/EPB)
#define AGS 68     // LDS agg row stride (shorts)

typedef unsigned short u16x8 __attribute__((ext_vector_type(8)));
typedef __bf16 bf16x8 __attribute__((ext_vector_type(8)));
typedef float f32x4 __attribute__((ext_vector_type(4)));

// ---------------- CSR build (round-11 proven, atomic-free at global) ----------------

__global__ __launch_bounds__(256) void k_bcount(const int* __restrict__ ei,
                                                int* __restrict__ relbase) {
  __shared__ int h[NBKT];
  const int tid = threadIdx.x;
  for (int i = tid; i < NBKT; i += 256) h[i] = 0;
  __syncthreads();
  int e = blockIdx.x * EPB + tid * 4;
  if (e < N_EDGES) {
    int4 d = *(const int4*)(ei + N_EDGES + e);
    atomicAdd(&h[d.x >> 8], 1);
    atomicAdd(&h[d.y >> 8], 1);
    atomicAdd(&h[d.z >> 8], 1);
    atomicAdd(&h[d.w >> 8], 1);
  }
  __syncthreads();
  for (int i = tid; i < NBKT; i += 256)
    relbase[i * EB + blockIdx.x] = h[i];  // bucket-major
}

__global__ __launch_bounds__(256) void k_scan_bkt(int* __restrict__ relbase,
                                                  int* __restrict__ bktsum) {
  __shared__ int sd[256];
  __shared__ int carry;
  const int i = blockIdx.x;
  const int tid = threadIdx.x;
  if (tid == 0) carry = 0;
  __syncthreads();
  int* p = relbase + i * EB;
  for (int c0 = 0; c0 < EB; c0 += 256) {
    int idx = c0 + tid;
    int v = (idx < EB) ? p[idx] : 0;
    sd[tid] = v;
    __syncthreads();
    for (int ofs = 1; ofs < 256; ofs <<= 1) {
      int t = (tid >= ofs) ? sd[tid - ofs] : 0;
      __syncthreads();
      sd[tid] += t;
      __syncthreads();
    }
    int excl = carry + sd[tid] - v;
    if (idx < EB) p[idx] = excl;
    __syncthreads();
    if (tid == 255) carry += sd[255];
    __syncthreads();
  }
  if (tid == 0) bktsum[i] = carry;
}

__global__ __launch_bounds__(512) void k_scan_start(const int* __restrict__ bktsum,
                                                    int* __restrict__ bktstart) {
  __shared__ int sd[512];
  const int tid = threadIdx.x;
  int v = (tid < NBKT) ? bktsum[tid] : 0;
  sd[tid] = v;
  __syncthreads();
  for (int ofs = 1; ofs < 512; ofs <<= 1) {
    int t = (tid >= ofs) ? sd[tid - ofs] : 0;
    __syncthreads();
    sd[tid] += t;
    __syncthreads();
  }
  if (tid < NBKT) bktstart[tid] = sd[tid] - v;
}

__global__ __launch_bounds__(256) void k_group(const int* __restrict__ ei,
                                               const int* __restrict__ relbase,
                                               const int* __restrict__ bktstart,
                                               int* __restrict__ grouped) {
  __shared__ int cur[NBKT];
  const int tid = threadIdx.x;
  const int b = blockIdx.x;
  for (int i = tid; i < NBKT; i += 256)
    cur[i] = bktstart[i] + relbase[i * EB + b];
  __syncthreads();
  int e = b * EPB + tid * 4;
  if (e < N_EDGES) {
    int4 s = *(const int4*)(ei + e);
    int4 d = *(const int4*)(ei + N_EDGES + e);
    int p;
    p = atomicAdd(&cur[d.x >> 8], 1); grouped[p] = s.x | ((d.x & 255) << 17);
    p = atomicAdd(&cur[d.y >> 8], 1); grouped[p] = s.y | ((d.y & 255) << 17);
    p = atomicAdd(&cur[d.z >> 8], 1); grouped[p] = s.z | ((d.z & 255) << 17);
    p = atomicAdd(&cur[d.w >> 8], 1); grouped[p] = s.w | ((d.w & 255) << 17);
  }
}

__global__ __launch_bounds__(256) void k_build(const int* __restrict__ grouped,
                                               const int* __restrict__ bktstart,
                                               const int* __restrict__ bktsum,
                                               int* __restrict__ deg,
                                               int* __restrict__ cursor,
                                               int* __restrict__ ssrc) {
  __shared__ int cnt[256];
  __shared__ int sloc[256];
  __shared__ int cur2[256];
  const int i = blockIdx.x;
  const int tid = threadIdx.x;
  const int gstart = bktstart[i];
  const int gnum = bktsum[i];
  cnt[tid] = 0;
  __syncthreads();
  for (int j = tid; j < gnum; j += 256)
    atomicAdd(&cnt[((unsigned)grouped[gstart + j]) >> 17], 1);
  __syncthreads();
  int v = cnt[tid];
  sloc[tid] = v;
  __syncthreads();
  for (int ofs = 1; ofs < 256; ofs <<= 1) {
    int t = (tid >= ofs) ? sloc[tid - ofs] : 0;
    __syncthreads();
    sloc[tid] += t;
    __syncthreads();
  }
  int excl = sloc[tid] - v;
  int node = i * 256 + tid;
  if (node < N_NODES) {
    deg[node] = v;
    cursor[node] = gstart + excl;
  }
  cur2[tid] = gstart + excl;
  __syncthreads();
  for (int j = tid; j < gnum; j += 256) {
    int g = grouped[gstart + j];
    int p = atomicAdd(&cur2[((unsigned)g) >> 17], 1);
    ssrc[p] = g & 0x1ffff;
  }
}

// ---------------- helpers ----------------

static __device__ inline unsigned short f2bf_bits(float v) {
  __hip_bfloat16 h = __float2bfloat16(v);
  return *reinterpret_cast<unsigned short*>(&h);
}

static __device__ inline void add_bf8(float* a, uint4 v) {
  unsigned int b;
  b = v.x << 16;         a[0] += *(float*)&b;
  b = v.x & 0xffff0000u; a[1] += *(float*)&b;
  b = v.y << 16;         a[2] += *(float*)&b;
  b = v.y & 0xffff0000u; a[3] += *(float*)&b;
  b = v.z << 16;         a[4] += *(float*)&b;
  b = v.z & 0xffff0000u; a[5] += *(float*)&b;
  b = v.w << 16;         a[6] += *(float*)&b;
  b = v.w & 0xffff0000u; a[7] += *(float*)&b;
}

static __device__ inline void add_fp8x8(float* a, uint2 v) {
  __hip_fp8_e4m3 t;
#pragma unroll
  for (int j = 0; j < 4; ++j) {
    t.__x = (__hip_fp8_storage_t)((v.x >> (8 * j)) & 0xff);
    a[j] += (float)t;
  }
#pragma unroll
  for (int j = 0; j < 4; ++j) {
    t.__x = (__hip_fp8_storage_t)((v.y >> (8 * j)) & 0xff);
    a[4 + j] += (float)t;
  }
}

// x f32 -> fp8 e4m3 table (layer-1 gather source; lives in d_out lower half)
__global__ __launch_bounds__(256) void k_cvt8(const float* __restrict__ x,
                                              unsigned char* __restrict__ x8) {
  long i = (long)(blockIdx.x * 256 + threadIdx.x) * 4;
  if (i >= (long)N_NODES * D) return;
  float4 v = *(const float4*)(x + i);
  uchar4 c;
  c.x = __hip_fp8_e4m3(v.x).__x;
  c.y = __hip_fp8_e4m3(v.y).__x;
  c.z = __hip_fp8_e4m3(v.z).__x;
  c.w = __hip_fp8_e4m3(v.w).__x;
  *(uchar4*)(x8 + i) = c;
}

// ---------------- fused gather + MFMA GEMM + ELU + BN ----------------
// Phase 1 (round-9 proven gather): 8-lane group per node, 32 groups, 2 passes;
// agg accumulated f32 then staged bf16 in LDS (8.7 KB only).
// Phase 2 (round-10 proven MFMA): A = [agg(LDS) | root(global)], B = weights
// loaded per-ot (16 VGPR peak instead of 64 -- protects gather occupancy).

template <bool G_FP8, bool ROOT_F32, bool OUT_BF16>
__global__ __launch_bounds__(256) void sage_fused_mfma(
    const int* __restrict__ cursor, const int* __restrict__ deg_a,
    const int* __restrict__ ssrc,
    const void* __restrict__ gsrc,   // gather table: fp8 or bf16 [N][D]
    const void* __restrict__ rootp,  // root rows: f32 or bf16 [N][D]
    const float* __restrict__ wl, const float* __restrict__ bl,
    const float* __restrict__ wr,
    const float* __restrict__ gamma, const float* __restrict__ beta,
    const float* __restrict__ mean, const float* __restrict__ var,
    void* __restrict__ out) {
  __shared__ unsigned short agg_t[64 * AGS];  // bf16 agg, 8704 B
  const int tid = threadIdx.x;
  const int base = blockIdx.x * 64;
  const int grp = tid >> 3;  // 8-lane group = node, 0..31
  const int q8 = tid & 7;    // 8-feature chunk

  // ---- phase 1: gather-aggregate into LDS ----
  for (int p = 0; p < 2; ++p) {
    int r = p * 32 + grp;
    int n = base + r;
    float a[8] = {0.f, 0.f, 0.f, 0.f, 0.f, 0.f, 0.f, 0.f};
    if (n < N_NODES) {
      int st = cursor[n];
      int dg = deg_a[n];
      int u = 0;
      if constexpr (G_FP8) {
        const unsigned char* gs = (const unsigned char*)gsrc;
        for (; u + 8 <= dg; u += 8) {
          int s0 = ssrc[st + u + 0], s1 = ssrc[st + u + 1];
          int s2 = ssrc[st + u + 2], s3 = ssrc[st + u + 3];
          int s4 = ssrc[st + u + 4], s5 = ssrc[st + u + 5];
          int s6 = ssrc[st + u + 6], s7 = ssrc[st + u + 7];
          uint2 v0 = *((const uint2*)(gs + (long)s0 * D) + q8);
          uint2 v1 = *((const uint2*)(gs + (long)s1 * D) + q8);
          uint2 v2 = *((const uint2*)(gs + (long)s2 * D) + q8);
          uint2 v3 = *((const uint2*)(gs + (long)s3 * D) + q8);
          uint2 v4 = *((const uint2*)(gs + (long)s4 * D) + q8);
          uint2 v5 = *((const uint2*)(gs + (long)s5 * D) + q8);
          uint2 v6 = *((const uint2*)(gs + (long)s6 * D) + q8);
          uint2 v7 = *((const uint2*)(gs + (long)s7 * D) + q8);
          add_fp8x8(a, v0); add_fp8x8(a, v1); add_fp8x8(a, v2); add_fp8x8(a, v3);
          add_fp8x8(a, v4); add_fp8x8(a, v5); add_fp8x8(a, v6); add_fp8x8(a, v7);
        }
        for (; u < dg; ++u) {
          uint2 v = *((const uint2*)(gs + (long)ssrc[st + u] * D) + q8);
          add_fp8x8(a, v);
        }
      } else {
        const unsigned short* gs = (const unsigned short*)gsrc;
        for (; u + 8 <= dg; u += 8) {
          int s0 = ssrc[st + u + 0], s1 = ssrc[st + u + 1];
          int s2 = ssrc[st + u + 2], s3 = ssrc[st + u + 3];
          int s4 = ssrc[st + u + 4], s5 = ssrc[st + u + 5];
          int s6 = ssrc[st + u + 6], s7 = ssrc[st + u + 7];
          uint4 v0 = *((const uint4*)(gs + (long)s0 * D) + q8);
          uint4 v1 = *((const uint4*)(gs + (long)s1 * D) + q8);
          uint4 v2 = *((const uint4*)(gs + (long)s2 * D) + q8);
          uint4 v3 = *((const uint4*)(gs + (long)s3 * D) + q8);
          uint4 v4 = *((const uint4*)(gs + (long)s4 * D) + q8);
          uint4 v5 = *((const uint4*)(gs + (long)s5 * D) + q8);
          uint4 v6 = *((const uint4*)(gs + (long)s6 * D) + q8);
          uint4 v7 = *((const uint4*)(gs + (long)s7 * D) + q8);
          add_bf8(a, v0); add_bf8(a, v1); add_bf8(a, v2); add_bf8(a, v3);
          add_bf8(a, v4); add_bf8(a, v5); add_bf8(a, v6); add_bf8(a, v7);
        }
        for (; u < dg; ++u) {
          uint4 v = *((const uint4*)(gs + (long)ssrc[st + u] * D) + q8);
          add_bf8(a, v);
        }
      }
      float invd = 1.0f / fmaxf((float)dg, 1.0f);
#pragma unroll
      for (int j = 0; j < 8; ++j) a[j] *= invd;
    }
    ushort4 u0, u1;
    u0.x = f2bf_bits(a[0]); u0.y = f2bf_bits(a[1]);
    u0.z = f2bf_bits(a[2]); u0.w = f2bf_bits(a[3]);
    u1.x = f2bf_bits(a[4]); u1.y = f2bf_bits(a[5]);
    u1.z = f2bf_bits(a[6]); u1.w = f2bf_bits(a[7]);
    *(ushort4*)&agg_t[r * AGS + q8 * 8 + 0] = u0;
    *(ushort4*)&agg_t[r * AGS + q8 * 8 + 4] = u1;
  }
  __syncthreads();

  // ---- phase 2: MFMA ----
  const int lane = tid & 63;
  const int wv = tid >> 6;
  const int c16 = lane & 15;     // A-row / B-col / D-col
  const int kg = lane >> 4;      // k-slice / D-row-group
  const int node0 = base + wv * 16;
  const int rloc = wv * 16 + c16;

  bf16x8 afr[4];
  afr[0] = __builtin_bit_cast(bf16x8, *(const u16x8*)&agg_t[rloc * AGS + kg * 8]);
  afr[1] = __builtin_bit_cast(bf16x8, *(const u16x8*)&agg_t[rloc * AGS + 32 + kg * 8]);
  long nrow = node0 + c16;
  long nclamp = (nrow < N_NODES) ? nrow : (N_NODES - 1);
  if constexpr (ROOT_F32) {
    const float* rp = (const float*)rootp + nclamp * D;
#pragma unroll
    for (int kt = 0; kt < 2; ++kt) {
      float4 f0 = *(const float4*)(rp + kt * 32 + kg * 8);
      float4 f1 = *(const float4*)(rp + kt * 32 + kg * 8 + 4);
      u16x8 u;
      u[0] = f2bf_bits(f0.x); u[1] = f2bf_bits(f0.y);
      u[2] = f2bf_bits(f0.z); u[3] = f2bf_bits(f0.w);
      u[4] = f2bf_bits(f1.x); u[5] = f2bf_bits(f1.y);
      u[6] = f2bf_bits(f1.z); u[7] = f2bf_bits(f1.w);
      afr[2 + kt] = __builtin_bit_cast(bf16x8, u);
    }
  } else {
    const unsigned short* rp = (const unsigned short*)rootp + nclamp * D;
    afr[2] = __builtin_bit_cast(bf16x8, *(const u16x8*)(rp + kg * 8));
    afr[3] = __builtin_bit_cast(bf16x8, *(const u16x8*)(rp + 32 + kg * 8));
  }

  f32x4 acc[4];
#pragma unroll
  for (int ot = 0; ot < 4; ++ot) acc[ot] = (f32x4){0.f, 0.f, 0.f, 0.f};
#pragma unroll
  for (int ot = 0; ot < 4; ++ot) {
    bf16x8 bfr[4];
#pragma unroll
    for (int kt = 0; kt < 4; ++kt) {
      const float* wsrc = (kt < 2) ? wl : wr;
      const float* p = wsrc + (long)(ot * 16 + c16) * 64 + (kt & 1) * 32 + kg * 8;
      float4 f0 = *(const float4*)p;
      float4 f1 = *(const float4*)(p + 4);
      u16x8 u;
      u[0] = f2bf_bits(f0.x); u[1] = f2bf_bits(f0.y);
      u[2] = f2bf_bits(f0.z); u[3] = f2bf_bits(f0.w);
      u[4] = f2bf_bits(f1.x); u[5] = f2bf_bits(f1.y);
      u[6] = f2bf_bits(f1.z); u[7] = f2bf_bits(f1.w);
      bfr[kt] = __builtin_bit_cast(bf16x8, u);
    }
#pragma unroll
    for (int kt = 0; kt < 4; ++kt)
      acc[ot] = __builtin_amdgcn_mfma_f32_16x16x32_bf16(afr[kt], bfr[kt],
                                                        acc[ot], 0, 0, 0);
  }

  // ---- epilogue ----
  float scv[4], shv[4], blv[4];
#pragma unroll
  for (int ot = 0; ot < 4; ++ot) {
    int ch = ot * 16 + c16;
    float sc = gamma[ch] * rsqrtf(var[ch] + BN_EPS);
    scv[ot] = sc;
    shv[ot] = beta[ch] - mean[ch] * sc;
    blv[ot] = bl[ch];
  }
#pragma unroll
  for (int r = 0; r < 4; ++r) {
    long node_out = node0 + kg * 4 + r;
    if (node_out < N_NODES) {
#pragma unroll
      for (int ot = 0; ot < 4; ++ot) {
        float v = acc[ot][r] + blv[ot];
        v = v > 0.f ? v : expm1f(v);
        v = v * scv[ot] + shv[ot];
        if constexpr (OUT_BF16) {
          ((unsigned short*)out)[node_out * D + ot * 16 + c16] = f2bf_bits(v);
        } else {
          ((float*)out)[node_out * D + ot * 16 + c16] = v;
        }
      }
    }
  }
}

// ---------------- launch ----------------

extern "C" void kernel_launch(void* const* d_in, const int* in_sizes, int n_in,
                              void* d_out, int out_size, void* d_ws, size_t ws_size,
                              hipStream_t stream) {
  const float* x     = (const float*)d_in[0];
  const int*   ei    = (const int*)d_in[1];
  const float* w1_l  = (const float*)d_in[2];
  const float* b1_l  = (const float*)d_in[3];
  const float* w1_r  = (const float*)d_in[4];
  const float* w2_l  = (const float*)d_in[5];
  const float* b2_l  = (const float*)d_in[6];
  const float* w2_r  = (const float*)d_in[7];
  const float* bn1_g = (const float*)d_in[8];
  const float* bn1_b = (const float*)d_in[9];
  const float* bn1_m = (const float*)d_in[10];
  const float* bn1_v = (const float*)d_in[11];
  const float* bn2_g = (const float*)d_in[12];
  const float* bn2_b = (const float*)d_in[13];
  const float* bn2_m = (const float*)d_in[14];
  const float* bn2_v = (const float*)d_in[15];

  // ws layout (~20.0 MB):
  int* deg      = (int*)d_ws;            // [100096]
  int* cursor   = deg + 100096;          // [100096]
  int* bktsum   = cursor + 100096;       // [512]
  int* bktstart = bktsum + 512;          // [512]
  int* ssrc     = bktstart + 512;        // [E]
  unsigned short* h1 = (unsigned short*)(ssrc + N_EDGES);  // bf16 [N*D], 12.8 MB
  // aliases of the h1 region (dead before fused1 writes h1):
  int* grouped  = (int*)h1;              // [E] 6.4 MB  (dead after k_build)
  int* relbase  = grouped + N_EDGES;     // [NBKT*EB] 2.44 MB (dead after k_group)

  // d_out: x8 fp8 table in lower quarter (6.4 MB), written by k_cvt8,
  // consumed by fused1; fused2 overwrites ALL of d_out with the final output.
  unsigned char* x8 = (unsigned char*)d_out;

  const int tiles = (N_NODES + 63) / 64;  // 1563

  // CSR build: no global atomics, no memset
  k_bcount<<<EB, 256, 0, stream>>>(ei, relbase);
  k_scan_bkt<<<NBKT, 256, 0, stream>>>(relbase, bktsum);
  k_scan_start<<<1, 512, 0, stream>>>(bktsum, bktstart);
  k_group<<<EB, 256, 0, stream>>>(ei, relbase, bktstart, grouped);
  k_build<<<NBKT, 256, 0, stream>>>(grouped, bktstart, bktsum, deg, cursor, ssrc);

  k_cvt8<<<(N_NODES * D / 4 + 255) / 256, 256, 0, stream>>>(x, x8);

  // layer 1: fused gather(fp8 x8) + MFMA(root = f32 x) -> bf16 h1 (ws)
  sage_fused_mfma<true, true, true><<<tiles, 256, 0, stream>>>(
      cursor, deg, ssrc, x8, x, w1_l, b1_l, w1_r,
      bn1_g, bn1_b, bn1_m, bn1_v, h1);

  // layer 2: fused gather(bf16 h1) + MFMA(root = bf16 h1) -> f32 d_out
  sage_fused_mfma<false, false, false><<<tiles, 256, 0, stream>>>(
      cursor, deg, ssrc, h1, h1, w2_l, b2_l, w2_r,
      bn2_g, bn2_b, bn2_m, bn2_v, d_out);
}

// Round 14
// 176.408 us; speedup vs baseline: 1.0980x; 1.0980x over previous
//
#include <hip/hip_runtime.h>
#include <hip/hip_bf16.h>
#include <hip/hip_fp8.h>

#define N_NODES 100000
#define N_EDGES 1600000
#define D 64
#define BN_EPS 1e-5f
#define NBKT 391   // buckets of 256 nodes: ceil(100000/256)
#define EPB 1024   // edges per block in pass A/B
#define EB 1563    // ceil(N_EDGES/EPB)
#define AGS 68     // LDS agg row stride (shorts)

typedef unsigned short u16x8 __attribute__((ext_vector_type(8)));
typedef __bf16 bf16x8 __attribute__((ext_vector_type(8)));
typedef float f32x4 __attribute__((ext_vector_type(4)));

// ---------------- CSR build (round-11 proven, atomic-free at global) ----------------

__global__ __launch_bounds__(256) void k_bcount(const int* __restrict__ ei,
                                                int* __restrict__ relbase) {
  __shared__ int h[NBKT];
  const int tid = threadIdx.x;
  for (int i = tid; i < NBKT; i += 256) h[i] = 0;
  __syncthreads();
  int e = blockIdx.x * EPB + tid * 4;
  if (e < N_EDGES) {
    int4 d = *(const int4*)(ei + N_EDGES + e);
    atomicAdd(&h[d.x >> 8], 1);
    atomicAdd(&h[d.y >> 8], 1);
    atomicAdd(&h[d.z >> 8], 1);
    atomicAdd(&h[d.w >> 8], 1);
  }
  __syncthreads();
  for (int i = tid; i < NBKT; i += 256)
    relbase[i * EB + blockIdx.x] = h[i];  // bucket-major
}

__global__ __launch_bounds__(256) void k_scan_bkt(int* __restrict__ relbase,
                                                  int* __restrict__ bktsum) {
  __shared__ int sd[256];
  __shared__ int carry;
  const int i = blockIdx.x;
  const int tid = threadIdx.x;
  if (tid == 0) carry = 0;
  __syncthreads();
  int* p = relbase + i * EB;
  for (int c0 = 0; c0 < EB; c0 += 256) {
    int idx = c0 + tid;
    int v = (idx < EB) ? p[idx] : 0;
    sd[tid] = v;
    __syncthreads();
    for (int ofs = 1; ofs < 256; ofs <<= 1) {
      int t = (tid >= ofs) ? sd[tid - ofs] : 0;
      __syncthreads();
      sd[tid] += t;
      __syncthreads();
    }
    int excl = carry + sd[tid] - v;
    if (idx < EB) p[idx] = excl;
    __syncthreads();
    if (tid == 255) carry += sd[255];
    __syncthreads();
  }
  if (tid == 0) bktsum[i] = carry;
}

__global__ __launch_bounds__(512) void k_scan_start(const int* __restrict__ bktsum,
                                                    int* __restrict__ bktstart) {
  __shared__ int sd[512];
  const int tid = threadIdx.x;
  int v = (tid < NBKT) ? bktsum[tid] : 0;
  sd[tid] = v;
  __syncthreads();
  for (int ofs = 1; ofs < 512; ofs <<= 1) {
    int t = (tid >= ofs) ? sd[tid - ofs] : 0;
    __syncthreads();
    sd[tid] += t;
    __syncthreads();
  }
  if (tid < NBKT) bktstart[tid] = sd[tid] - v;
}

__global__ __launch_bounds__(256) void k_group(const int* __restrict__ ei,
                                               const int* __restrict__ relbase,
                                               const int* __restrict__ bktstart,
                                               int* __restrict__ grouped) {
  __shared__ int cur[NBKT];
  const int tid = threadIdx.x;
  const int b = blockIdx.x;
  for (int i = tid; i < NBKT; i += 256)
    cur[i] = bktstart[i] + relbase[i * EB + b];
  __syncthreads();
  int e = b * EPB + tid * 4;
  if (e < N_EDGES) {
    int4 s = *(const int4*)(ei + e);
    int4 d = *(const int4*)(ei + N_EDGES + e);
    int p;
    p = atomicAdd(&cur[d.x >> 8], 1); grouped[p] = s.x | ((d.x & 255) << 17);
    p = atomicAdd(&cur[d.y >> 8], 1); grouped[p] = s.y | ((d.y & 255) << 17);
    p = atomicAdd(&cur[d.z >> 8], 1); grouped[p] = s.z | ((d.z & 255) << 17);
    p = atomicAdd(&cur[d.w >> 8], 1); grouped[p] = s.w | ((d.w & 255) << 17);
  }
}

__global__ __launch_bounds__(256) void k_build(const int* __restrict__ grouped,
                                               const int* __restrict__ bktstart,
                                               const int* __restrict__ bktsum,
                                               int* __restrict__ deg,
                                               int* __restrict__ cursor,
                                               int* __restrict__ ssrc) {
  __shared__ int cnt[256];
  __shared__ int sloc[256];
  __shared__ int cur2[256];
  const int i = blockIdx.x;
  const int tid = threadIdx.x;
  const int gstart = bktstart[i];
  const int gnum = bktsum[i];
  cnt[tid] = 0;
  __syncthreads();
  for (int j = tid; j < gnum; j += 256)
    atomicAdd(&cnt[((unsigned)grouped[gstart + j]) >> 17], 1);
  __syncthreads();
  int v = cnt[tid];
  sloc[tid] = v;
  __syncthreads();
  for (int ofs = 1; ofs < 256; ofs <<= 1) {
    int t = (tid >= ofs) ? sloc[tid - ofs] : 0;
    __syncthreads();
    sloc[tid] += t;
    __syncthreads();
  }
  int excl = sloc[tid] - v;
  int node = i * 256 + tid;
  if (node < N_NODES) {
    deg[node] = v;
    cursor[node] = gstart + excl;
  }
  cur2[tid] = gstart + excl;
  __syncthreads();
  for (int j = tid; j < gnum; j += 256) {
    int g = grouped[gstart + j];
    int p = atomicAdd(&cur2[((unsigned)g) >> 17], 1);
    ssrc[p] = g & 0x1ffff;
  }
}

// ---------------- helpers ----------------

static __device__ inline unsigned short f2bf_bits(float v) {
  __hip_bfloat16 h = __float2bfloat16(v);
  return *reinterpret_cast<unsigned short*>(&h);
}

static __device__ inline void add_bf8(float* a, uint4 v) {
  unsigned int b;
  b = v.x << 16;         a[0] += *(float*)&b;
  b = v.x & 0xffff0000u; a[1] += *(float*)&b;
  b = v.y << 16;         a[2] += *(float*)&b;
  b = v.y & 0xffff0000u; a[3] += *(float*)&b;
  b = v.z << 16;         a[4] += *(float*)&b;
  b = v.z & 0xffff0000u; a[5] += *(float*)&b;
  b = v.w << 16;         a[6] += *(float*)&b;
  b = v.w & 0xffff0000u; a[7] += *(float*)&b;
}

static __device__ inline void add_fp8x8(float* a, uint2 v) {
  __hip_fp8_e4m3 t;
#pragma unroll
  for (int j = 0; j < 4; ++j) {
    t.__x = (__hip_fp8_storage_t)((v.x >> (8 * j)) & 0xff);
    a[j] += (float)t;
  }
#pragma unroll
  for (int j = 0; j < 4; ++j) {
    t.__x = (__hip_fp8_storage_t)((v.y >> (8 * j)) & 0xff);
    a[4 + j] += (float)t;
  }
}

// weights f32 -> bf16, once: wb = [w1_l | w1_r | w2_l | w2_r], each 4096 elems
__global__ __launch_bounds__(256) void k_cvtw(const float* __restrict__ w0,
                                              const float* __restrict__ w1,
                                              const float* __restrict__ w2,
                                              const float* __restrict__ w3,
                                              unsigned short* __restrict__ wb) {
  int i = blockIdx.x * 256 + threadIdx.x;  // 0..4095, 4 floats each
  if (i >= 4096) return;
  const float* src = (i < 1024) ? w0 : (i < 2048) ? w1 : (i < 3072) ? w2 : w3;
  int off = (i & 1023) * 4;
  float4 v = *(const float4*)(src + off);
  ushort4 u;
  u.x = f2bf_bits(v.x); u.y = f2bf_bits(v.y);
  u.z = f2bf_bits(v.z); u.w = f2bf_bits(v.w);
  *(ushort4*)(wb + (i >> 10) * 4096 + off) = u;
}

// x f32 -> fp8 table (d_out lower quarter) + bf16 root table (d_out upper half)
__global__ __launch_bounds__(256) void k_cvt8x(const float* __restrict__ x,
                                               unsigned char* __restrict__ x8,
                                               unsigned short* __restrict__ xb) {
  long i = (long)(blockIdx.x * 256 + threadIdx.x) * 4;
  if (i >= (long)N_NODES * D) return;
  float4 v = *(const float4*)(x + i);
  uchar4 c;
  c.x = __hip_fp8_e4m3(v.x).__x;
  c.y = __hip_fp8_e4m3(v.y).__x;
  c.z = __hip_fp8_e4m3(v.z).__x;
  c.w = __hip_fp8_e4m3(v.w).__x;
  *(uchar4*)(x8 + i) = c;
  ushort4 u;
  u.x = f2bf_bits(v.x); u.y = f2bf_bits(v.y);
  u.z = f2bf_bits(v.z); u.w = f2bf_bits(v.w);
  *(ushort4*)(xb + i) = u;
}

// ---------------- fused gather + MFMA GEMM + ELU + BN ----------------
// Phase 1 (round-9 proven): 8-lane group per node, agg staged bf16 in LDS.
// Phase 2 (round-10 proven MFMA): A = [agg(LDS) | root(bf16 global)],
// B = pre-converted bf16 weights (direct u16x8 loads, zero VALU prep).

template <bool G_FP8, bool OUT_BF16>
__global__ __launch_bounds__(256) void sage_fused_mfma(
    const int* __restrict__ cursor, const int* __restrict__ deg_a,
    const int* __restrict__ ssrc,
    const void* __restrict__ gsrc,              // gather: fp8 or bf16 [N][D]
    const unsigned short* __restrict__ rootp,   // root rows: bf16 [N][D]
    const unsigned short* __restrict__ wbl,     // bf16 Wl [64][64]
    const unsigned short* __restrict__ wbr,     // bf16 Wr [64][64]
    const float* __restrict__ bl,
    const float* __restrict__ gamma, const float* __restrict__ beta,
    const float* __restrict__ mean, const float* __restrict__ var,
    void* __restrict__ out) {
  __shared__ unsigned short agg_t[64 * AGS];  // bf16 agg, 8704 B
  const int tid = threadIdx.x;
  const int base = blockIdx.x * 64;
  const int grp = tid >> 3;  // 8-lane group = node, 0..31
  const int q8 = tid & 7;    // 8-feature chunk

  // ---- phase 1: gather-aggregate into LDS ----
  for (int p = 0; p < 2; ++p) {
    int r = p * 32 + grp;
    int n = base + r;
    float a[8] = {0.f, 0.f, 0.f, 0.f, 0.f, 0.f, 0.f, 0.f};
    if (n < N_NODES) {
      int st = cursor[n];
      int dg = deg_a[n];
      int u = 0;
      if constexpr (G_FP8) {
        const unsigned char* gs = (const unsigned char*)gsrc;
        for (; u + 8 <= dg; u += 8) {
          int s0 = ssrc[st + u + 0], s1 = ssrc[st + u + 1];
          int s2 = ssrc[st + u + 2], s3 = ssrc[st + u + 3];
          int s4 = ssrc[st + u + 4], s5 = ssrc[st + u + 5];
          int s6 = ssrc[st + u + 6], s7 = ssrc[st + u + 7];
          uint2 v0 = *((const uint2*)(gs + (long)s0 * D) + q8);
          uint2 v1 = *((const uint2*)(gs + (long)s1 * D) + q8);
          uint2 v2 = *((const uint2*)(gs + (long)s2 * D) + q8);
          uint2 v3 = *((const uint2*)(gs + (long)s3 * D) + q8);
          uint2 v4 = *((const uint2*)(gs + (long)s4 * D) + q8);
          uint2 v5 = *((const uint2*)(gs + (long)s5 * D) + q8);
          uint2 v6 = *((const uint2*)(gs + (long)s6 * D) + q8);
          uint2 v7 = *((const uint2*)(gs + (long)s7 * D) + q8);
          add_fp8x8(a, v0); add_fp8x8(a, v1); add_fp8x8(a, v2); add_fp8x8(a, v3);
          add_fp8x8(a, v4); add_fp8x8(a, v5); add_fp8x8(a, v6); add_fp8x8(a, v7);
        }
        for (; u < dg; ++u) {
          uint2 v = *((const uint2*)(gs + (long)ssrc[st + u] * D) + q8);
          add_fp8x8(a, v);
        }
      } else {
        const unsigned short* gs = (const unsigned short*)gsrc;
        for (; u + 8 <= dg; u += 8) {
          int s0 = ssrc[st + u + 0], s1 = ssrc[st + u + 1];
          int s2 = ssrc[st + u + 2], s3 = ssrc[st + u + 3];
          int s4 = ssrc[st + u + 4], s5 = ssrc[st + u + 5];
          int s6 = ssrc[st + u + 6], s7 = ssrc[st + u + 7];
          uint4 v0 = *((const uint4*)(gs + (long)s0 * D) + q8);
          uint4 v1 = *((const uint4*)(gs + (long)s1 * D) + q8);
          uint4 v2 = *((const uint4*)(gs + (long)s2 * D) + q8);
          uint4 v3 = *((const uint4*)(gs + (long)s3 * D) + q8);
          uint4 v4 = *((const uint4*)(gs + (long)s4 * D) + q8);
          uint4 v5 = *((const uint4*)(gs + (long)s5 * D) + q8);
          uint4 v6 = *((const uint4*)(gs + (long)s6 * D) + q8);
          uint4 v7 = *((const uint4*)(gs + (long)s7 * D) + q8);
          add_bf8(a, v0); add_bf8(a, v1); add_bf8(a, v2); add_bf8(a, v3);
          add_bf8(a, v4); add_bf8(a, v5); add_bf8(a, v6); add_bf8(a, v7);
        }
        for (; u < dg; ++u) {
          uint4 v = *((const uint4*)(gs + (long)ssrc[st + u] * D) + q8);
          add_bf8(a, v);
        }
      }
      float invd = 1.0f / fmaxf((float)dg, 1.0f);
#pragma unroll
      for (int j = 0; j < 8; ++j) a[j] *= invd;
    }
    ushort4 u0, u1;
    u0.x = f2bf_bits(a[0]); u0.y = f2bf_bits(a[1]);
    u0.z = f2bf_bits(a[2]); u0.w = f2bf_bits(a[3]);
    u1.x = f2bf_bits(a[4]); u1.y = f2bf_bits(a[5]);
    u1.z = f2bf_bits(a[6]); u1.w = f2bf_bits(a[7]);
    *(ushort4*)&agg_t[r * AGS + q8 * 8 + 0] = u0;
    *(ushort4*)&agg_t[r * AGS + q8 * 8 + 4] = u1;
  }
  __syncthreads();

  // ---- phase 2: MFMA, all operands bf16 direct loads ----
  const int lane = tid & 63;
  const int wv = tid >> 6;
  const int c16 = lane & 15;     // A-row / B-col / D-col
  const int kg = lane >> 4;      // k-slice / D-row-group
  const int node0 = base + wv * 16;
  const int rloc = wv * 16 + c16;

  bf16x8 afr[4];
  afr[0] = __builtin_bit_cast(bf16x8, *(const u16x8*)&agg_t[rloc * AGS + kg * 8]);
  afr[1] = __builtin_bit_cast(bf16x8, *(const u16x8*)&agg_t[rloc * AGS + 32 + kg * 8]);
  long nrow = node0 + c16;
  long nclamp = (nrow < N_NODES) ? nrow : (N_NODES - 1);
  {
    const unsigned short* rp = rootp + nclamp * D;
    afr[2] = __builtin_bit_cast(bf16x8, *(const u16x8*)(rp + kg * 8));
    afr[3] = __builtin_bit_cast(bf16x8, *(const u16x8*)(rp + 32 + kg * 8));
  }

  f32x4 acc[4];
#pragma unroll
  for (int ot = 0; ot < 4; ++ot) acc[ot] = (f32x4){0.f, 0.f, 0.f, 0.f};
#pragma unroll
  for (int ot = 0; ot < 4; ++ot) {
    const long wrow = (long)(ot * 16 + c16) * 64;
    bf16x8 b0 = __builtin_bit_cast(bf16x8, *(const u16x8*)(wbl + wrow + kg * 8));
    bf16x8 b1 = __builtin_bit_cast(bf16x8, *(const u16x8*)(wbl + wrow + 32 + kg * 8));
    bf16x8 b2 = __builtin_bit_cast(bf16x8, *(const u16x8*)(wbr + wrow + kg * 8));
    bf16x8 b3 = __builtin_bit_cast(bf16x8, *(const u16x8*)(wbr + wrow + 32 + kg * 8));
    acc[ot] = __builtin_amdgcn_mfma_f32_16x16x32_bf16(afr[0], b0, acc[ot], 0, 0, 0);
    acc[ot] = __builtin_amdgcn_mfma_f32_16x16x32_bf16(afr[1], b1, acc[ot], 0, 0, 0);
    acc[ot] = __builtin_amdgcn_mfma_f32_16x16x32_bf16(afr[2], b2, acc[ot], 0, 0, 0);
    acc[ot] = __builtin_amdgcn_mfma_f32_16x16x32_bf16(afr[3], b3, acc[ot], 0, 0, 0);
  }

  // ---- epilogue ----
  float scv[4], shv[4], blv[4];
#pragma unroll
  for (int ot = 0; ot < 4; ++ot) {
    int ch = ot * 16 + c16;
    float sc = gamma[ch] * rsqrtf(var[ch] + BN_EPS);
    scv[ot] = sc;
    shv[ot] = beta[ch] - mean[ch] * sc;
    blv[ot] = bl[ch];
  }
#pragma unroll
  for (int r = 0; r < 4; ++r) {
    long node_out = node0 + kg * 4 + r;
    if (node_out < N_NODES) {
#pragma unroll
      for (int ot = 0; ot < 4; ++ot) {
        float v = acc[ot][r] + blv[ot];
        v = v > 0.f ? v : expm1f(v);
        v = v * scv[ot] + shv[ot];
        if constexpr (OUT_BF16) {
          ((unsigned short*)out)[node_out * D + ot * 16 + c16] = f2bf_bits(v);
        } else {
          ((float*)out)[node_out * D + ot * 16 + c16] = v;
        }
      }
    }
  }
}

// ---------------- launch ----------------

extern "C" void kernel_launch(void* const* d_in, const int* in_sizes, int n_in,
                              void* d_out, int out_size, void* d_ws, size_t ws_size,
                              hipStream_t stream) {
  const float* x     = (const float*)d_in[0];
  const int*   ei    = (const int*)d_in[1];
  const float* w1_l  = (const float*)d_in[2];
  const float* b1_l  = (const float*)d_in[3];
  const float* w1_r  = (const float*)d_in[4];
  const float* w2_l  = (const float*)d_in[5];
  const float* b2_l  = (const float*)d_in[6];
  const float* w2_r  = (const float*)d_in[7];
  const float* bn1_g = (const float*)d_in[8];
  const float* bn1_b = (const float*)d_in[9];
  const float* bn1_m = (const float*)d_in[10];
  const float* bn1_v = (const float*)d_in[11];
  const float* bn2_g = (const float*)d_in[12];
  const float* bn2_b = (const float*)d_in[13];
  const float* bn2_m = (const float*)d_in[14];
  const float* bn2_v = (const float*)d_in[15];

  // ws layout (~20.03 MB; round 1 proved ws >= 25.7 MB):
  int* deg      = (int*)d_ws;            // [100096]
  int* cursor   = deg + 100096;          // [100096]
  int* bktsum   = cursor + 100096;       // [512]
  int* bktstart = bktsum + 512;          // [512]
  int* ssrc     = bktstart + 512;        // [E]
  unsigned short* h1 = (unsigned short*)(ssrc + N_EDGES);  // bf16 [N*D], 12.8 MB
  unsigned short* wb = h1 + (size_t)N_NODES * D;           // bf16 weights, 32 KB
  // aliases of the h1 region (dead before fused1 writes h1):
  int* grouped  = (int*)h1;              // [E] 6.4 MB  (dead after k_build)
  int* relbase  = grouped + N_EDGES;     // [NBKT*EB] 2.44 MB (dead after k_group)

  // d_out: x8 fp8 table (lower quarter, 6.4 MB) + xb bf16 root (upper half,
  // 12.8 MB); both consumed by fused1, then fused2 overwrites ALL of d_out.
  unsigned char* x8  = (unsigned char*)d_out;
  unsigned short* xb = (unsigned short*)d_out + (size_t)N_NODES * D;

  const int tiles = (N_NODES + 63) / 64;  // 1563

  k_cvtw<<<16, 256, 0, stream>>>(w1_l, w1_r, w2_l, w2_r, wb);

  // CSR build: no global atomics, no memset
  k_bcount<<<EB, 256, 0, stream>>>(ei, relbase);
  k_scan_bkt<<<NBKT, 256, 0, stream>>>(relbase, bktsum);
  k_scan_start<<<1, 512, 0, stream>>>(bktsum, bktstart);
  k_group<<<EB, 256, 0, stream>>>(ei, relbase, bktstart, grouped);
  k_build<<<NBKT, 256, 0, stream>>>(grouped, bktstart, bktsum, deg, cursor, ssrc);

  k_cvt8x<<<(N_NODES * D / 4 + 255) / 256, 256, 0, stream>>>(x, x8, xb);

  // layer 1: fused gather(fp8 x8) + MFMA(root = bf16 xb) -> bf16 h1 (ws)
  sage_fused_mfma<true, true><<<tiles, 256, 0, stream>>>(
      cursor, deg, ssrc, x8, xb, wb, wb + 4096, b1_l,
      bn1_g, bn1_b, bn1_m, bn1_v, h1);

  // layer 2: fused gather(bf16 h1) + MFMA(root = bf16 h1) -> f32 d_out
  sage_fused_mfma<false, false><<<tiles, 256, 0, stream>>>(
      cursor, deg, ssrc, h1, h1, wb + 8192, wb + 12288, b2_l,
      bn2_g, bn2_b, bn2_m, bn2_v, d_out);
}

// Round 15
// 164.479 us; speedup vs baseline: 1.1776x; 1.0725x over previous
//
#include <hip/hip_runtime.h>
#include <hip/hip_bf16.h>
#include <hip/hip_fp8.h>

#define N_NODES 100000
#define N_EDGES 1600000
#define D 64
#define BN_EPS 1e-5f
#define NBKT 391   // buckets of 256 nodes
#define EPB 4096   // edges per block in pass A/B
#define EB 391     // ceil(N_EDGES/EPB)
#define AGS 68     // LDS agg row stride (shorts)
#define WS_NEED 26437632ull

typedef unsigned short u16x8 __attribute__((ext_vector_type(8)));
typedef __bf16 bf16x8 __attribute__((ext_vector_type(8)));
typedef float f32x4 __attribute__((ext_vector_type(4)));

// ---------------- CSR build (atomic-free at global scope) ----------------

__global__ __launch_bounds__(256) void k_bcount(const int* __restrict__ ei,
                                                int* __restrict__ relbase) {
  __shared__ int h[NBKT];
  const int tid = threadIdx.x;
  for (int i = tid; i < NBKT; i += 256) h[i] = 0;
  __syncthreads();
#pragma unroll
  for (int k = 0; k < 4; ++k) {
    int e = blockIdx.x * EPB + k * 1024 + tid * 4;
    if (e < N_EDGES) {
      int4 d = *(const int4*)(ei + N_EDGES + e);
      atomicAdd(&h[d.x >> 8], 1);
      atomicAdd(&h[d.y >> 8], 1);
      atomicAdd(&h[d.z >> 8], 1);
      atomicAdd(&h[d.w >> 8], 1);
    }
  }
  __syncthreads();
  for (int i = tid; i < NBKT; i += 256)
    relbase[i * EB + blockIdx.x] = h[i];  // bucket-major
}

__global__ __launch_bounds__(256) void k_scan_bkt(int* __restrict__ relbase,
                                                  int* __restrict__ bktsum) {
  __shared__ int sd[256];
  __shared__ int carry;
  const int i = blockIdx.x;
  const int tid = threadIdx.x;
  if (tid == 0) carry = 0;
  __syncthreads();
  int* p = relbase + i * EB;
  for (int c0 = 0; c0 < EB; c0 += 256) {
    int idx = c0 + tid;
    int v = (idx < EB) ? p[idx] : 0;
    sd[tid] = v;
    __syncthreads();
    for (int ofs = 1; ofs < 256; ofs <<= 1) {
      int t = (tid >= ofs) ? sd[tid - ofs] : 0;
      __syncthreads();
      sd[tid] += t;
      __syncthreads();
    }
    int excl = carry + sd[tid] - v;
    if (idx < EB) p[idx] = excl;
    __syncthreads();
    if (tid == 255) carry += sd[255];
    __syncthreads();
  }
  if (tid == 0) bktsum[i] = carry;
}

__global__ __launch_bounds__(512) void k_scan_start(const int* __restrict__ bktsum,
                                                    int* __restrict__ bktstart) {
  __shared__ int sd[512];
  const int tid = threadIdx.x;
  int v = (tid < NBKT) ? bktsum[tid] : 0;
  sd[tid] = v;
  __syncthreads();
  for (int ofs = 1; ofs < 512; ofs <<= 1) {
    int t = (tid >= ofs) ? sd[tid - ofs] : 0;
    __syncthreads();
    sd[tid] += t;
    __syncthreads();
  }
  if (tid < NBKT) bktstart[tid] = sd[tid] - v;
}

__global__ __launch_bounds__(256) void k_group(const int* __restrict__ ei,
                                               const int* __restrict__ relbase,
                                               const int* __restrict__ bktstart,
                                               int* __restrict__ grouped) {
  __shared__ int cur[NBKT];
  const int tid = threadIdx.x;
  const int b = blockIdx.x;
  for (int i = tid; i < NBKT; i += 256)
    cur[i] = bktstart[i] + relbase[i * EB + b];
  __syncthreads();
#pragma unroll
  for (int k = 0; k < 4; ++k) {
    int e = b * EPB + k * 1024 + tid * 4;
    if (e < N_EDGES) {
      int4 s = *(const int4*)(ei + e);
      int4 d = *(const int4*)(ei + N_EDGES + e);
      int p;
      p = atomicAdd(&cur[d.x >> 8], 1); grouped[p] = s.x | ((d.x & 255) << 17);
      p = atomicAdd(&cur[d.y >> 8], 1); grouped[p] = s.y | ((d.y & 255) << 17);
      p = atomicAdd(&cur[d.z >> 8], 1); grouped[p] = s.z | ((d.z & 255) << 17);
      p = atomicAdd(&cur[d.w >> 8], 1); grouped[p] = s.w | ((d.w & 255) << 17);
    }
  }
}

// Pass C: per bucket, count per (node, src-quarter), scan 1024, place.
// Neighbor lists come out quarter-ordered (src>>15): all blocks sweep the
// table quarter 0->3 roughly in phase -> concurrent working set ~1/4 table
// (fits per-XCD L2) -> gather misses become L2 hits.
__global__ __launch_bounds__(256) void k_build(const int* __restrict__ grouped,
                                               const int* __restrict__ bktstart,
                                               const int* __restrict__ bktsum,
                                               int* __restrict__ deg,
                                               int* __restrict__ cursor,
                                               int* __restrict__ ssrc) {
  __shared__ int cnt[1024];
  __shared__ int sd[256];
  __shared__ int carry;
  const int i = blockIdx.x;
  const int tid = threadIdx.x;
  const int gstart = bktstart[i];
  const int gnum = bktsum[i];
  for (int k = tid; k < 1024; k += 256) cnt[k] = 0;
  if (tid == 0) carry = 0;
  __syncthreads();
  for (int j = tid; j < gnum; j += 256) {
    int g = grouped[gstart + j];
    int key = ((((unsigned)g) >> 17) << 2) | ((g & 0x1ffff) >> 15);
    atomicAdd(&cnt[key], 1);
  }
  __syncthreads();
  int c0 = cnt[tid * 4 + 0], c1 = cnt[tid * 4 + 1];
  int c2 = cnt[tid * 4 + 2], c3 = cnt[tid * 4 + 3];
  __syncthreads();
  // exclusive scan of cnt[1024] in place (4 chunks + carry)
  for (int c = 0; c < 4; ++c) {
    int idx = c * 256 + tid;
    int v = cnt[idx];
    sd[tid] = v;
    __syncthreads();
    for (int ofs = 1; ofs < 256; ofs <<= 1) {
      int t = (tid >= ofs) ? sd[tid - ofs] : 0;
      __syncthreads();
      sd[tid] += t;
      __syncthreads();
    }
    cnt[idx] = carry + sd[tid] - v;
    __syncthreads();
    if (tid == 255) carry += sd[255];
    __syncthreads();
  }
  int node = i * 256 + tid;
  if (node < N_NODES) {
    deg[node] = c0 + c1 + c2 + c3;
    cursor[node] = gstart + cnt[tid * 4];
  }
  __syncthreads();
  for (int j = tid; j < gnum; j += 256) {
    int g = grouped[gstart + j];
    int src = g & 0x1ffff;
    int key = ((((unsigned)g) >> 17) << 2) | (src >> 15);
    int p = gstart + atomicAdd(&cnt[key], 1);
    ssrc[p] = src;
  }
}

// ---------------- helpers ----------------

static __device__ inline unsigned short f2bf_bits(float v) {
  __hip_bfloat16 h = __float2bfloat16(v);
  return *reinterpret_cast<unsigned short*>(&h);
}

static __device__ inline void add_bf8(float* a, uint4 v) {
  unsigned int b;
  b = v.x << 16;         a[0] += *(float*)&b;
  b = v.x & 0xffff0000u; a[1] += *(float*)&b;
  b = v.y << 16;         a[2] += *(float*)&b;
  b = v.y & 0xffff0000u; a[3] += *(float*)&b;
  b = v.z << 16;         a[4] += *(float*)&b;
  b = v.z & 0xffff0000u; a[5] += *(float*)&b;
  b = v.w << 16;         a[6] += *(float*)&b;
  b = v.w & 0xffff0000u; a[7] += *(float*)&b;
}

static __device__ inline void add_fp8x8(float* a, uint2 v) {
  __hip_fp8_e4m3 t;
#pragma unroll
  for (int j = 0; j < 4; ++j) {
    t.__x = (__hip_fp8_storage_t)((v.x >> (8 * j)) & 0xff);
    a[j] += (float)t;
  }
#pragma unroll
  for (int j = 0; j < 4; ++j) {
    t.__x = (__hip_fp8_storage_t)((v.y >> (8 * j)) & 0xff);
    a[4 + j] += (float)t;
  }
}

// weights f32 -> bf16: wb = [w1_l | w1_r | w2_l | w2_r]
__global__ __launch_bounds__(256) void k_cvtw(const float* __restrict__ w0,
                                              const float* __restrict__ w1,
                                              const float* __restrict__ w2,
                                              const float* __restrict__ w3,
                                              unsigned short* __restrict__ wb) {
  int i = blockIdx.x * 256 + threadIdx.x;  // 0..4095, 4 floats each
  if (i >= 4096) return;
  const float* src = (i < 1024) ? w0 : (i < 2048) ? w1 : (i < 3072) ? w2 : w3;
  int off = (i & 1023) * 4;
  float4 v = *(const float4*)(src + off);
  ushort4 u;
  u.x = f2bf_bits(v.x); u.y = f2bf_bits(v.y);
  u.z = f2bf_bits(v.z); u.w = f2bf_bits(v.w);
  *(ushort4*)(wb + (i >> 10) * 4096 + off) = u;
}

// x f32 -> fp8 table (d_out lower quarter) + bf16 root table (d_out upper half)
__global__ __launch_bounds__(256) void k_cvt8x(const float* __restrict__ x,
                                               unsigned char* __restrict__ x8,
                                               unsigned short* __restrict__ xb) {
  long i = (long)(blockIdx.x * 256 + threadIdx.x) * 4;
  if (i >= (long)N_NODES * D) return;
  float4 v = *(const float4*)(x + i);
  uchar4 c;
  c.x = __hip_fp8_e4m3(v.x).__x;
  c.y = __hip_fp8_e4m3(v.y).__x;
  c.z = __hip_fp8_e4m3(v.z).__x;
  c.w = __hip_fp8_e4m3(v.w).__x;
  *(uchar4*)(x8 + i) = c;
  ushort4 u;
  u.x = f2bf_bits(v.x); u.y = f2bf_bits(v.y);
  u.z = f2bf_bits(v.z); u.w = f2bf_bits(v.w);
  *(ushort4*)(xb + i) = u;
}

// ---------------- fused gather + MFMA GEMM + ELU + BN ----------------
// OUT_MODE: 0 = f32 out; 1 = bf16 out; 2 = bf16 out + fp8 copy (out8).

template <bool G_FP8, int OUT_MODE>
__global__ __launch_bounds__(256) void sage_fused_mfma(
    const int* __restrict__ cursor, const int* __restrict__ deg_a,
    const int* __restrict__ ssrc,
    const void* __restrict__ gsrc,              // gather: fp8 or bf16 [N][D]
    const unsigned short* __restrict__ rootp,   // root rows: bf16 [N][D]
    const unsigned short* __restrict__ wbl,     // bf16 Wl [64][64]
    const unsigned short* __restrict__ wbr,     // bf16 Wr [64][64]
    const float* __restrict__ bl,
    const float* __restrict__ gamma, const float* __restrict__ beta,
    const float* __restrict__ mean, const float* __restrict__ var,
    void* __restrict__ out, unsigned char* __restrict__ out8) {
  __shared__ unsigned short agg_t[64 * AGS];  // bf16 agg, 8704 B
  const int tid = threadIdx.x;
  const int base = blockIdx.x * 64;
  const int grp = tid >> 3;  // 8-lane group = node, 0..31
  const int q8 = tid & 7;    // 8-feature chunk

  // ---- phase 1: gather-aggregate into LDS ----
  for (int p = 0; p < 2; ++p) {
    int r = p * 32 + grp;
    int n = base + r;
    float a[8] = {0.f, 0.f, 0.f, 0.f, 0.f, 0.f, 0.f, 0.f};
    if (n < N_NODES) {
      int st = cursor[n];
      int dg = deg_a[n];
      int u = 0;
      if constexpr (G_FP8) {
        const unsigned char* gs = (const unsigned char*)gsrc;
        for (; u + 8 <= dg; u += 8) {
          int s0 = ssrc[st + u + 0], s1 = ssrc[st + u + 1];
          int s2 = ssrc[st + u + 2], s3 = ssrc[st + u + 3];
          int s4 = ssrc[st + u + 4], s5 = ssrc[st + u + 5];
          int s6 = ssrc[st + u + 6], s7 = ssrc[st + u + 7];
          uint2 v0 = *((const uint2*)(gs + (long)s0 * D) + q8);
          uint2 v1 = *((const uint2*)(gs + (long)s1 * D) + q8);
          uint2 v2 = *((const uint2*)(gs + (long)s2 * D) + q8);
          uint2 v3 = *((const uint2*)(gs + (long)s3 * D) + q8);
          uint2 v4 = *((const uint2*)(gs + (long)s4 * D) + q8);
          uint2 v5 = *((const uint2*)(gs + (long)s5 * D) + q8);
          uint2 v6 = *((const uint2*)(gs + (long)s6 * D) + q8);
          uint2 v7 = *((const uint2*)(gs + (long)s7 * D) + q8);
          add_fp8x8(a, v0); add_fp8x8(a, v1); add_fp8x8(a, v2); add_fp8x8(a, v3);
          add_fp8x8(a, v4); add_fp8x8(a, v5); add_fp8x8(a, v6); add_fp8x8(a, v7);
        }
        for (; u < dg; ++u) {
          uint2 v = *((const uint2*)(gs + (long)ssrc[st + u] * D) + q8);
          add_fp8x8(a, v);
        }
      } else {
        const unsigned short* gs = (const unsigned short*)gsrc;
        for (; u + 8 <= dg; u += 8) {
          int s0 = ssrc[st + u + 0], s1 = ssrc[st + u + 1];
          int s2 = ssrc[st + u + 2], s3 = ssrc[st + u + 3];
          int s4 = ssrc[st + u + 4], s5 = ssrc[st + u + 5];
          int s6 = ssrc[st + u + 6], s7 = ssrc[st + u + 7];
          uint4 v0 = *((const uint4*)(gs + (long)s0 * D) + q8);
          uint4 v1 = *((const uint4*)(gs + (long)s1 * D) + q8);
          uint4 v2 = *((const uint4*)(gs + (long)s2 * D) + q8);
          uint4 v3 = *((const uint4*)(gs + (long)s3 * D) + q8);
          uint4 v4 = *((const uint4*)(gs + (long)s4 * D) + q8);
          uint4 v5 = *((const uint4*)(gs + (long)s5 * D) + q8);
          uint4 v6 = *((const uint4*)(gs + (long)s6 * D) + q8);
          uint4 v7 = *((const uint4*)(gs + (long)s7 * D) + q8);
          add_bf8(a, v0); add_bf8(a, v1); add_bf8(a, v2); add_bf8(a, v3);
          add_bf8(a, v4); add_bf8(a, v5); add_bf8(a, v6); add_bf8(a, v7);
        }
        for (; u < dg; ++u) {
          uint4 v = *((const uint4*)(gs + (long)ssrc[st + u] * D) + q8);
          add_bf8(a, v);
        }
      }
      float invd = 1.0f / fmaxf((float)dg, 1.0f);
#pragma unroll
      for (int j = 0; j < 8; ++j) a[j] *= invd;
    }
    ushort4 u0, u1;
    u0.x = f2bf_bits(a[0]); u0.y = f2bf_bits(a[1]);
    u0.z = f2bf_bits(a[2]); u0.w = f2bf_bits(a[3]);
    u1.x = f2bf_bits(a[4]); u1.y = f2bf_bits(a[5]);
    u1.z = f2bf_bits(a[6]); u1.w = f2bf_bits(a[7]);
    *(ushort4*)&agg_t[r * AGS + q8 * 8 + 0] = u0;
    *(ushort4*)&agg_t[r * AGS + q8 * 8 + 4] = u1;
  }
  __syncthreads();

  // ---- phase 2: MFMA, all operands bf16 direct loads ----
  const int lane = tid & 63;
  const int wv = tid >> 6;
  const int c16 = lane & 15;
  const int kg = lane >> 4;
  const int node0 = base + wv * 16;
  const int rloc = wv * 16 + c16;

  bf16x8 afr[4];
  afr[0] = __builtin_bit_cast(bf16x8, *(const u16x8*)&agg_t[rloc * AGS + kg * 8]);
  afr[1] = __builtin_bit_cast(bf16x8, *(const u16x8*)&agg_t[rloc * AGS + 32 + kg * 8]);
  long nrow = node0 + c16;
  long nclamp = (nrow < N_NODES) ? nrow : (N_NODES - 1);
  {
    const unsigned short* rp = rootp + nclamp * D;
    afr[2] = __builtin_bit_cast(bf16x8, *(const u16x8*)(rp + kg * 8));
    afr[3] = __builtin_bit_cast(bf16x8, *(const u16x8*)(rp + 32 + kg * 8));
  }

  f32x4 acc[4];
#pragma unroll
  for (int ot = 0; ot < 4; ++ot) acc[ot] = (f32x4){0.f, 0.f, 0.f, 0.f};
#pragma unroll
  for (int ot = 0; ot < 4; ++ot) {
    const long wrow = (long)(ot * 16 + c16) * 64;
    bf16x8 b0 = __builtin_bit_cast(bf16x8, *(const u16x8*)(wbl + wrow + kg * 8));
    bf16x8 b1 = __builtin_bit_cast(bf16x8, *(const u16x8*)(wbl + wrow + 32 + kg * 8));
    bf16x8 b2 = __builtin_bit_cast(bf16x8, *(const u16x8*)(wbr + wrow + kg * 8));
    bf16x8 b3 = __builtin_bit_cast(bf16x8, *(const u16x8*)(wbr + wrow + 32 + kg * 8));
    acc[ot] = __builtin_amdgcn_mfma_f32_16x16x32_bf16(afr[0], b0, acc[ot], 0, 0, 0);
    acc[ot] = __builtin_amdgcn_mfma_f32_16x16x32_bf16(afr[1], b1, acc[ot], 0, 0, 0);
    acc[ot] = __builtin_amdgcn_mfma_f32_16x16x32_bf16(afr[2], b2, acc[ot], 0, 0, 0);
    acc[ot] = __builtin_amdgcn_mfma_f32_16x16x32_bf16(afr[3], b3, acc[ot], 0, 0, 0);
  }

  // ---- epilogue ----
  float scv[4], shv[4], blv[4];
#pragma unroll
  for (int ot = 0; ot < 4; ++ot) {
    int ch = ot * 16 + c16;
    float sc = gamma[ch] * rsqrtf(var[ch] + BN_EPS);
    scv[ot] = sc;
    shv[ot] = beta[ch] - mean[ch] * sc;
    blv[ot] = bl[ch];
  }
#pragma unroll
  for (int r = 0; r < 4; ++r) {
    long node_out = node0 + kg * 4 + r;
    if (node_out < N_NODES) {
#pragma unroll
      for (int ot = 0; ot < 4; ++ot) {
        float v = acc[ot][r] + blv[ot];
        v = v > 0.f ? v : expm1f(v);
        v = v * scv[ot] + shv[ot];
        if constexpr (OUT_MODE == 0) {
          ((float*)out)[node_out * D + ot * 16 + c16] = v;
        } else {
          ((unsigned short*)out)[node_out * D + ot * 16 + c16] = f2bf_bits(v);
          if constexpr (OUT_MODE == 2) {
            out8[node_out * D + ot * 16 + c16] = __hip_fp8_e4m3(v).__x;
          }
        }
      }
    }
  }
}

// ---------------- launch ----------------

extern "C" void kernel_launch(void* const* d_in, const int* in_sizes, int n_in,
                              void* d_out, int out_size, void* d_ws, size_t ws_size,
                              hipStream_t stream) {
  const float* x     = (const float*)d_in[0];
  const int*   ei    = (const int*)d_in[1];
  const float* w1_l  = (const float*)d_in[2];
  const float* b1_l  = (const float*)d_in[3];
  const float* w1_r  = (const float*)d_in[4];
  const float* w2_l  = (const float*)d_in[5];
  const float* b2_l  = (const float*)d_in[6];
  const float* w2_r  = (const float*)d_in[7];
  const float* bn1_g = (const float*)d_in[8];
  const float* bn1_b = (const float*)d_in[9];
  const float* bn1_m = (const float*)d_in[10];
  const float* bn1_v = (const float*)d_in[11];
  const float* bn2_g = (const float*)d_in[12];
  const float* bn2_b = (const float*)d_in[13];
  const float* bn2_m = (const float*)d_in[14];
  const float* bn2_v = (const float*)d_in[15];

  // ws layout:
  int* deg      = (int*)d_ws;            // [100096]
  int* cursor   = deg + 100096;          // [100096]
  int* bktsum   = cursor + 100096;       // [512]
  int* bktstart = bktsum + 512;          // [512]
  int* ssrc     = bktstart + 512;        // [E]
  unsigned short* h1 = (unsigned short*)(ssrc + N_EDGES);  // bf16 [N*D], 12.8 MB
  unsigned short* wb = h1 + (size_t)N_NODES * D;           // bf16 weights, 32 KB
  unsigned char* h18 = (unsigned char*)(wb + 16384);       // fp8 [N*D], 6.4 MB (guarded)
  // aliases of the h1 region (dead before fused1 writes h1):
  int* grouped  = (int*)h1;              // [E] 6.4 MB (dead after k_build)
  int* relbase  = grouped + N_EDGES;     // [NBKT*EB] 0.61 MB (dead after k_group)

  const bool use_h18 = ws_size >= WS_NEED;

  // d_out: x8 fp8 (lower quarter) + xb bf16 root (upper half); both consumed
  // by fused1, then fused2 overwrites ALL of d_out.
  unsigned char* x8  = (unsigned char*)d_out;
  unsigned short* xb = (unsigned short*)d_out + (size_t)N_NODES * D;

  const int tiles = (N_NODES + 63) / 64;  // 1563

  k_cvtw<<<16, 256, 0, stream>>>(w1_l, w1_r, w2_l, w2_r, wb);

  k_bcount<<<EB, 256, 0, stream>>>(ei, relbase);
  k_scan_bkt<<<NBKT, 256, 0, stream>>>(relbase, bktsum);
  k_scan_start<<<1, 512, 0, stream>>>(bktsum, bktstart);
  k_group<<<EB, 256, 0, stream>>>(ei, relbase, bktstart, grouped);
  k_build<<<NBKT, 256, 0, stream>>>(grouped, bktstart, bktsum, deg, cursor, ssrc);

  k_cvt8x<<<(N_NODES * D / 4 + 255) / 256, 256, 0, stream>>>(x, x8, xb);

  if (use_h18) {
    // layer 1: gather fp8 x8, root bf16 xb -> h1 (bf16) + h18 (fp8)
    sage_fused_mfma<true, 2><<<tiles, 256, 0, stream>>>(
        cursor, deg, ssrc, x8, xb, wb, wb + 4096, b1_l,
        bn1_g, bn1_b, bn1_m, bn1_v, h1, h18);
    // layer 2: gather fp8 h18, root bf16 h1 -> f32 d_out
    sage_fused_mfma<true, 0><<<tiles, 256, 0, stream>>>(
        cursor, deg, ssrc, h18, h1, wb + 8192, wb + 12288, b2_l,
        bn2_g, bn2_b, bn2_m, bn2_v, d_out, nullptr);
  } else {
    sage_fused_mfma<true, 1><<<tiles, 256, 0, stream>>>(
        cursor, deg, ssrc, x8, xb, wb, wb + 4096, b1_l,
        bn1_g, bn1_b, bn1_m, bn1_v, h1, nullptr);
    sage_fused_mfma<false, 0><<<tiles, 256, 0, stream>>>(
        cursor, deg, ssrc, h1, h1, wb + 8192, wb + 12288, b2_l,
        bn2_g, bn2_b, bn2_m, bn2_v, d_out, nullptr);
  }
}

// Round 16
// 146.408 us; speedup vs baseline: 1.3230x; 1.1234x over previous
//
#include <hip/hip_runtime.h>
#include <hip/hip_bf16.h>
#include <hip/hip_fp8.h>

#define N_NODES 100000
#define N_EDGES 1600000
#define D 64
#define BN_EPS 1e-5f
#define NBKT 391   // buckets of 256 nodes
#define EPB 4096   // edges per block in pass A/B
#define EB 391     // ceil(N_EDGES/EPB)
#define AGS 68     // LDS agg row stride (shorts)
#define ICAP 48    // staged indices per node (P(deg>48) ~ 0 at Poisson(16))
#define ISTR 52    // idx_t row stride: 52 mod 32 -> 8 distinct banks across groups
#define WS_NEED 26437632ull

typedef unsigned short u16x8 __attribute__((ext_vector_type(8)));
typedef __bf16 bf16x8 __attribute__((ext_vector_type(8)));
typedef float f32x4 __attribute__((ext_vector_type(4)));

static __device__ inline unsigned short f2bf_bits(float v) {
  __hip_bfloat16 h = __float2bfloat16(v);
  return *reinterpret_cast<unsigned short*>(&h);
}

// ---------------- CSR build (atomic-free at global scope) ----------------
// k_bcount also performs the x -> fp8/bf16 table conversions (independent
// work folded in to save a launch).

__global__ __launch_bounds__(256) void k_bcount_cvt(
    const int* __restrict__ ei, int* __restrict__ relbase,
    const float* __restrict__ x, unsigned char* __restrict__ x8,
    unsigned short* __restrict__ xb) {
  __shared__ int h[NBKT];
  const int tid = threadIdx.x;
  for (int i = tid; i < NBKT; i += 256) h[i] = 0;
  __syncthreads();
#pragma unroll
  for (int k = 0; k < 4; ++k) {
    int e = blockIdx.x * EPB + k * 1024 + tid * 4;
    if (e < N_EDGES) {
      int4 d = *(const int4*)(ei + N_EDGES + e);
      atomicAdd(&h[d.x >> 8], 1);
      atomicAdd(&h[d.y >> 8], 1);
      atomicAdd(&h[d.z >> 8], 1);
      atomicAdd(&h[d.w >> 8], 1);
    }
  }
  // folded conversion: grid-stride over N*D/4 float4 chunks
  for (long i = (long)blockIdx.x * 256 + tid; i < (long)N_NODES * D / 4;
       i += (long)EB * 256) {
    float4 v = *(const float4*)(x + i * 4);
    uchar4 c;
    c.x = __hip_fp8_e4m3(v.x).__x;
    c.y = __hip_fp8_e4m3(v.y).__x;
    c.z = __hip_fp8_e4m3(v.z).__x;
    c.w = __hip_fp8_e4m3(v.w).__x;
    *(uchar4*)(x8 + i * 4) = c;
    ushort4 u;
    u.x = f2bf_bits(v.x); u.y = f2bf_bits(v.y);
    u.z = f2bf_bits(v.z); u.w = f2bf_bits(v.w);
    *(ushort4*)(xb + i * 4) = u;
  }
  __syncthreads();
  for (int i = tid; i < NBKT; i += 256)
    relbase[i * EB + blockIdx.x] = h[i];  // bucket-major
}

__global__ __launch_bounds__(256) void k_scan_bkt(int* __restrict__ relbase,
                                                  int* __restrict__ bktsum) {
  __shared__ int sd[256];
  __shared__ int carry;
  const int i = blockIdx.x;
  const int tid = threadIdx.x;
  if (tid == 0) carry = 0;
  __syncthreads();
  int* p = relbase + i * EB;
  for (int c0 = 0; c0 < EB; c0 += 256) {
    int idx = c0 + tid;
    int v = (idx < EB) ? p[idx] : 0;
    sd[tid] = v;
    __syncthreads();
    for (int ofs = 1; ofs < 256; ofs <<= 1) {
      int t = (tid >= ofs) ? sd[tid - ofs] : 0;
      __syncthreads();
      sd[tid] += t;
      __syncthreads();
    }
    int excl = carry + sd[tid] - v;
    if (idx < EB) p[idx] = excl;
    __syncthreads();
    if (tid == 255) carry += sd[255];
    __syncthreads();
  }
  if (tid == 0) bktsum[i] = carry;
}

// single block: bucket-start scan + weight bf16 conversion (folded)
__global__ __launch_bounds__(512) void k_scan_start_cvtw(
    const int* __restrict__ bktsum, int* __restrict__ bktstart,
    const float* __restrict__ w0, const float* __restrict__ w1,
    const float* __restrict__ w2, const float* __restrict__ w3,
    unsigned short* __restrict__ wb) {
  __shared__ int sd[512];
  const int tid = threadIdx.x;
  int v = (tid < NBKT) ? bktsum[tid] : 0;
  sd[tid] = v;
  __syncthreads();
  for (int ofs = 1; ofs < 512; ofs <<= 1) {
    int t = (tid >= ofs) ? sd[tid - ofs] : 0;
    __syncthreads();
    sd[tid] += t;
    __syncthreads();
  }
  if (tid < NBKT) bktstart[tid] = sd[tid] - v;
  for (int i = tid; i < 4096; i += 512) {
    const float* src = (i < 1024) ? w0 : (i < 2048) ? w1 : (i < 3072) ? w2 : w3;
    int off = (i & 1023) * 4;
    float4 f = *(const float4*)(src + off);
    ushort4 u;
    u.x = f2bf_bits(f.x); u.y = f2bf_bits(f.y);
    u.z = f2bf_bits(f.z); u.w = f2bf_bits(f.w);
    *(ushort4*)(wb + (i >> 10) * 4096 + off) = u;
  }
}

__global__ __launch_bounds__(256) void k_group(const int* __restrict__ ei,
                                               const int* __restrict__ relbase,
                                               const int* __restrict__ bktstart,
                                               int* __restrict__ grouped) {
  __shared__ int cur[NBKT];
  const int tid = threadIdx.x;
  const int b = blockIdx.x;
  for (int i = tid; i < NBKT; i += 256)
    cur[i] = bktstart[i] + relbase[i * EB + b];
  __syncthreads();
#pragma unroll
  for (int k = 0; k < 4; ++k) {
    int e = b * EPB + k * 1024 + tid * 4;
    if (e < N_EDGES) {
      int4 s = *(const int4*)(ei + e);
      int4 d = *(const int4*)(ei + N_EDGES + e);
      int p;
      p = atomicAdd(&cur[d.x >> 8], 1); grouped[p] = s.x | ((d.x & 255) << 17);
      p = atomicAdd(&cur[d.y >> 8], 1); grouped[p] = s.y | ((d.y & 255) << 17);
      p = atomicAdd(&cur[d.z >> 8], 1); grouped[p] = s.z | ((d.z & 255) << 17);
      p = atomicAdd(&cur[d.w >> 8], 1); grouped[p] = s.w | ((d.w & 255) << 17);
    }
  }
}

// Pass C with src-quarter sub-ordering (round-15 proven).
__global__ __launch_bounds__(256) void k_build(const int* __restrict__ grouped,
                                               const int* __restrict__ bktstart,
                                               const int* __restrict__ bktsum,
                                               int* __restrict__ deg,
                                               int* __restrict__ cursor,
                                               int* __restrict__ ssrc) {
  __shared__ int cnt[1024];
  __shared__ int sd[256];
  __shared__ int carry;
  const int i = blockIdx.x;
  const int tid = threadIdx.x;
  const int gstart = bktstart[i];
  const int gnum = bktsum[i];
  for (int k = tid; k < 1024; k += 256) cnt[k] = 0;
  if (tid == 0) carry = 0;
  __syncthreads();
  for (int j = tid; j < gnum; j += 256) {
    int g = grouped[gstart + j];
    int key = ((((unsigned)g) >> 17) << 2) | ((g & 0x1ffff) >> 15);
    atomicAdd(&cnt[key], 1);
  }
  __syncthreads();
  int c0 = cnt[tid * 4 + 0], c1 = cnt[tid * 4 + 1];
  int c2 = cnt[tid * 4 + 2], c3 = cnt[tid * 4 + 3];
  __syncthreads();
  for (int c = 0; c < 4; ++c) {
    int idx = c * 256 + tid;
    int v = cnt[idx];
    sd[tid] = v;
    __syncthreads();
    for (int ofs = 1; ofs < 256; ofs <<= 1) {
      int t = (tid >= ofs) ? sd[tid - ofs] : 0;
      __syncthreads();
      sd[tid] += t;
      __syncthreads();
    }
    cnt[idx] = carry + sd[tid] - v;
    __syncthreads();
    if (tid == 255) carry += sd[255];
    __syncthreads();
  }
  int node = i * 256 + tid;
  if (node < N_NODES) {
    deg[node] = c0 + c1 + c2 + c3;
    cursor[node] = gstart + cnt[tid * 4];
  }
  __syncthreads();
  for (int j = tid; j < gnum; j += 256) {
    int g = grouped[gstart + j];
    int src = g & 0x1ffff;
    int key = ((((unsigned)g) >> 17) << 2) | (src >> 15);
    int p = gstart + atomicAdd(&cnt[key], 1);
    ssrc[p] = src;
  }
}

// ---------------- decode helpers ----------------

static __device__ inline void add_bf8(float* a, uint4 v) {
  unsigned int b;
  b = v.x << 16;         a[0] += *(float*)&b;
  b = v.x & 0xffff0000u; a[1] += *(float*)&b;
  b = v.y << 16;         a[2] += *(float*)&b;
  b = v.y & 0xffff0000u; a[3] += *(float*)&b;
  b = v.z << 16;         a[4] += *(float*)&b;
  b = v.z & 0xffff0000u; a[5] += *(float*)&b;
  b = v.w << 16;         a[6] += *(float*)&b;
  b = v.w & 0xffff0000u; a[7] += *(float*)&b;
}

static __device__ inline void add_fp8x8(float* a, uint2 v) {
  __hip_fp8_e4m3 t;
#pragma unroll
  for (int j = 0; j < 4; ++j) {
    t.__x = (__hip_fp8_storage_t)((v.x >> (8 * j)) & 0xff);
    a[j] += (float)t;
  }
#pragma unroll
  for (int j = 0; j < 4; ++j) {
    t.__x = (__hip_fp8_storage_t)((v.y >> (8 * j)) & 0xff);
    a[4 + j] += (float)t;
  }
}

// ---------------- fused gather + MFMA GEMM + ELU + BN ----------------
// Phase 1: LDS index staging (1 index-latency per node) + predicated
// full-width tail (no serial per-edge chains). Phase 2: round-10 MFMA.
// OUT_MODE: 0 = f32 out; 1 = bf16 out; 2 = bf16 out + fp8 copy (out8).

template <bool G_FP8, int OUT_MODE>
__global__ __launch_bounds__(256) void sage_fused_mfma(
    const int* __restrict__ cursor, const int* __restrict__ deg_a,
    const int* __restrict__ ssrc,
    const void* __restrict__ gsrc,              // gather: fp8 or bf16 [N][D]
    const unsigned short* __restrict__ rootp,   // root rows: bf16 [N][D]
    const unsigned short* __restrict__ wbl,     // bf16 Wl [64][64]
    const unsigned short* __restrict__ wbr,     // bf16 Wr [64][64]
    const float* __restrict__ bl,
    const float* __restrict__ gamma, const float* __restrict__ beta,
    const float* __restrict__ mean, const float* __restrict__ var,
    void* __restrict__ out, unsigned char* __restrict__ out8) {
  __shared__ unsigned short agg_t[64 * AGS];  // bf16 agg, 8704 B
  __shared__ int idx_t[32 * ISTR];            // staged indices, 6656 B
  const int tid = threadIdx.x;
  const int base = blockIdx.x * 64;
  const int grp = tid >> 3;  // 8-lane group = node, 0..31
  const int q8 = tid & 7;    // 8-feature chunk / stage lane

  for (int p = 0; p < 2; ++p) {
    int r = p * 32 + grp;
    int n = base + r;
    float a[8] = {0.f, 0.f, 0.f, 0.f, 0.f, 0.f, 0.f, 0.f};
    if (n < N_NODES) {
      int st = cursor[n];
      int dg = deg_a[n];
      int cap = dg < ICAP ? dg : ICAP;
      const int g0 = grp * ISTR;
      // stage all indices at once (6 predicated coalesced loads, 1 round-trip)
#pragma unroll
      for (int j = 0; j < 6; ++j) {
        int jj = q8 + j * 8;
        if (jj < cap) idx_t[g0 + jj] = ssrc[st + jj];
      }
      // wave-synchronous LDS: group writes then group reads, same wave.
      if constexpr (G_FP8) {
        const unsigned char* gs = (const unsigned char*)gsrc;
        for (int u = 0; u < cap; u += 8) {
          int rem = cap - u;  // 1..8
          int s0 = idx_t[g0 + u];
          int s1 = idx_t[g0 + u + (1 < rem ? 1 : 0)];
          int s2 = idx_t[g0 + u + (2 < rem ? 2 : 0)];
          int s3 = idx_t[g0 + u + (3 < rem ? 3 : 0)];
          int s4 = idx_t[g0 + u + (4 < rem ? 4 : 0)];
          int s5 = idx_t[g0 + u + (5 < rem ? 5 : 0)];
          int s6 = idx_t[g0 + u + (6 < rem ? 6 : 0)];
          int s7 = idx_t[g0 + u + (7 < rem ? 7 : 0)];
          uint2 v0 = *((const uint2*)(gs + (long)s0 * D) + q8);
          uint2 v1 = *((const uint2*)(gs + (long)s1 * D) + q8);
          uint2 v2 = *((const uint2*)(gs + (long)s2 * D) + q8);
          uint2 v3 = *((const uint2*)(gs + (long)s3 * D) + q8);
          uint2 v4 = *((const uint2*)(gs + (long)s4 * D) + q8);
          uint2 v5 = *((const uint2*)(gs + (long)s5 * D) + q8);
          uint2 v6 = *((const uint2*)(gs + (long)s6 * D) + q8);
          uint2 v7 = *((const uint2*)(gs + (long)s7 * D) + q8);
          // zero raw bytes beyond rem: fp8 0x00 decodes to 0.0
          v1.x = 1 < rem ? v1.x : 0u; v1.y = 1 < rem ? v1.y : 0u;
          v2.x = 2 < rem ? v2.x : 0u; v2.y = 2 < rem ? v2.y : 0u;
          v3.x = 3 < rem ? v3.x : 0u; v3.y = 3 < rem ? v3.y : 0u;
          v4.x = 4 < rem ? v4.x : 0u; v4.y = 4 < rem ? v4.y : 0u;
          v5.x = 5 < rem ? v5.x : 0u; v5.y = 5 < rem ? v5.y : 0u;
          v6.x = 6 < rem ? v6.x : 0u; v6.y = 6 < rem ? v6.y : 0u;
          v7.x = 7 < rem ? v7.x : 0u; v7.y = 7 < rem ? v7.y : 0u;
          add_fp8x8(a, v0); add_fp8x8(a, v1); add_fp8x8(a, v2); add_fp8x8(a, v3);
          add_fp8x8(a, v4); add_fp8x8(a, v5); add_fp8x8(a, v6); add_fp8x8(a, v7);
        }
        for (int u = cap; u < dg; ++u) {  // deg > ICAP fallback (rare)
          uint2 v = *((const uint2*)(gs + (long)ssrc[st + u] * D) + q8);
          add_fp8x8(a, v);
        }
      } else {
        const unsigned short* gs = (const unsigned short*)gsrc;
        for (int u = 0; u < cap; u += 8) {
          int rem = cap - u;
          int s0 = idx_t[g0 + u];
          int s1 = idx_t[g0 + u + (1 < rem ? 1 : 0)];
          int s2 = idx_t[g0 + u + (2 < rem ? 2 : 0)];
          int s3 = idx_t[g0 + u + (3 < rem ? 3 : 0)];
          int s4 = idx_t[g0 + u + (4 < rem ? 4 : 0)];
          int s5 = idx_t[g0 + u + (5 < rem ? 5 : 0)];
          int s6 = idx_t[g0 + u + (6 < rem ? 6 : 0)];
          int s7 = idx_t[g0 + u + (7 < rem ? 7 : 0)];
          uint4 v0 = *((const uint4*)(gs + (long)s0 * D) + q8);
          uint4 v1 = *((const uint4*)(gs + (long)s1 * D) + q8);
          uint4 v2 = *((const uint4*)(gs + (long)s2 * D) + q8);
          uint4 v3 = *((const uint4*)(gs + (long)s3 * D) + q8);
          uint4 v4 = *((const uint4*)(gs + (long)s4 * D) + q8);
          uint4 v5 = *((const uint4*)(gs + (long)s5 * D) + q8);
          uint4 v6 = *((const uint4*)(gs + (long)s6 * D) + q8);
          uint4 v7 = *((const uint4*)(gs + (long)s7 * D) + q8);
          if (1 >= rem) v1 = make_uint4(0, 0, 0, 0);
          if (2 >= rem) v2 = make_uint4(0, 0, 0, 0);
          if (3 >= rem) v3 = make_uint4(0, 0, 0, 0);
          if (4 >= rem) v4 = make_uint4(0, 0, 0, 0);
          if (5 >= rem) v5 = make_uint4(0, 0, 0, 0);
          if (6 >= rem) v6 = make_uint4(0, 0, 0, 0);
          if (7 >= rem) v7 = make_uint4(0, 0, 0, 0);
          add_bf8(a, v0); add_bf8(a, v1); add_bf8(a, v2); add_bf8(a, v3);
          add_bf8(a, v4); add_bf8(a, v5); add_bf8(a, v6); add_bf8(a, v7);
        }
        for (int u = cap; u < dg; ++u) {
          uint4 v = *((const uint4*)(gs + (long)ssrc[st + u] * D) + q8);
          add_bf8(a, v);
        }
      }
      float invd = 1.0f / fmaxf((float)dg, 1.0f);
#pragma unroll
      for (int j = 0; j < 8; ++j) a[j] *= invd;
    }
    ushort4 u0, u1;
    u0.x = f2bf_bits(a[0]); u0.y = f2bf_bits(a[1]);
    u0.z = f2bf_bits(a[2]); u0.w = f2bf_bits(a[3]);
    u1.x = f2bf_bits(a[4]); u1.y = f2bf_bits(a[5]);
    u1.z = f2bf_bits(a[6]); u1.w = f2bf_bits(a[7]);
    *(ushort4*)&agg_t[r * AGS + q8 * 8 + 0] = u0;
    *(ushort4*)&agg_t[r * AGS + q8 * 8 + 4] = u1;
  }
  __syncthreads();

  // ---- phase 2: MFMA, all operands bf16 direct loads (round-14 proven) ----
  const int lane = tid & 63;
  const int wv = tid >> 6;
  const int c16 = lane & 15;
  const int kg = lane >> 4;
  const int node0 = base + wv * 16;
  const int rloc = wv * 16 + c16;

  bf16x8 afr[4];
  afr[0] = __builtin_bit_cast(bf16x8, *(const u16x8*)&agg_t[rloc * AGS + kg * 8]);
  afr[1] = __builtin_bit_cast(bf16x8, *(const u16x8*)&agg_t[rloc * AGS + 32 + kg * 8]);
  long nrow = node0 + c16;
  long nclamp = (nrow < N_NODES) ? nrow : (N_NODES - 1);
  {
    const unsigned short* rp = rootp + nclamp * D;
    afr[2] = __builtin_bit_cast(bf16x8, *(const u16x8*)(rp + kg * 8));
    afr[3] = __builtin_bit_cast(bf16x8, *(const u16x8*)(rp + 32 + kg * 8));
  }

  f32x4 acc[4];
#pragma unroll
  for (int ot = 0; ot < 4; ++ot) acc[ot] = (f32x4){0.f, 0.f, 0.f, 0.f};
#pragma unroll
  for (int ot = 0; ot < 4; ++ot) {
    const long wrow = (long)(ot * 16 + c16) * 64;
    bf16x8 b0 = __builtin_bit_cast(bf16x8, *(const u16x8*)(wbl + wrow + kg * 8));
    bf16x8 b1 = __builtin_bit_cast(bf16x8, *(const u16x8*)(wbl + wrow + 32 + kg * 8));
    bf16x8 b2 = __builtin_bit_cast(bf16x8, *(const u16x8*)(wbr + wrow + kg * 8));
    bf16x8 b3 = __builtin_bit_cast(bf16x8, *(const u16x8*)(wbr + wrow + 32 + kg * 8));
    acc[ot] = __builtin_amdgcn_mfma_f32_16x16x32_bf16(afr[0], b0, acc[ot], 0, 0, 0);
    acc[ot] = __builtin_amdgcn_mfma_f32_16x16x32_bf16(afr[1], b1, acc[ot], 0, 0, 0);
    acc[ot] = __builtin_amdgcn_mfma_f32_16x16x32_bf16(afr[2], b2, acc[ot], 0, 0, 0);
    acc[ot] = __builtin_amdgcn_mfma_f32_16x16x32_bf16(afr[3], b3, acc[ot], 0, 0, 0);
  }

  // ---- epilogue ----
  float scv[4], shv[4], blv[4];
#pragma unroll
  for (int ot = 0; ot < 4; ++ot) {
    int ch = ot * 16 + c16;
    float sc = gamma[ch] * rsqrtf(var[ch] + BN_EPS);
    scv[ot] = sc;
    shv[ot] = beta[ch] - mean[ch] * sc;
    blv[ot] = bl[ch];
  }
#pragma unroll
  for (int r = 0; r < 4; ++r) {
    long node_out = node0 + kg * 4 + r;
    if (node_out < N_NODES) {
#pragma unroll
      for (int ot = 0; ot < 4; ++ot) {
        float v = acc[ot][r] + blv[ot];
        v = v > 0.f ? v : expm1f(v);
        v = v * scv[ot] + shv[ot];
        if constexpr (OUT_MODE == 0) {
          ((float*)out)[node_out * D + ot * 16 + c16] = v;
        } else {
          ((unsigned short*)out)[node_out * D + ot * 16 + c16] = f2bf_bits(v);
          if constexpr (OUT_MODE == 2) {
            out8[node_out * D + ot * 16 + c16] = __hip_fp8_e4m3(v).__x;
          }
        }
      }
    }
  }
}

// ---------------- launch ----------------

extern "C" void kernel_launch(void* const* d_in, const int* in_sizes, int n_in,
                              void* d_out, int out_size, void* d_ws, size_t ws_size,
                              hipStream_t stream) {
  const float* x     = (const float*)d_in[0];
  const int*   ei    = (const int*)d_in[1];
  const float* w1_l  = (const float*)d_in[2];
  const float* b1_l  = (const float*)d_in[3];
  const float* w1_r  = (const float*)d_in[4];
  const float* w2_l  = (const float*)d_in[5];
  const float* b2_l  = (const float*)d_in[6];
  const float* w2_r  = (const float*)d_in[7];
  const float* bn1_g = (const float*)d_in[8];
  const float* bn1_b = (const float*)d_in[9];
  const float* bn1_m = (const float*)d_in[10];
  const float* bn1_v = (const float*)d_in[11];
  const float* bn2_g = (const float*)d_in[12];
  const float* bn2_b = (const float*)d_in[13];
  const float* bn2_m = (const float*)d_in[14];
  const float* bn2_v = (const float*)d_in[15];

  // ws layout:
  int* deg      = (int*)d_ws;            // [100096]
  int* cursor   = deg + 100096;          // [100096]
  int* bktsum   = cursor + 100096;       // [512]
  int* bktstart = bktsum + 512;          // [512]
  int* ssrc     = bktstart + 512;        // [E]
  unsigned short* h1 = (unsigned short*)(ssrc + N_EDGES);  // bf16 [N*D], 12.8 MB
  unsigned short* wb = h1 + (size_t)N_NODES * D;           // bf16 weights, 32 KB
  unsigned char* h18 = (unsigned char*)(wb + 16384);       // fp8 [N*D], 6.4 MB
  // aliases of the h1 region (dead before fused1 writes h1):
  int* grouped  = (int*)h1;              // [E] 6.4 MB (dead after k_build)
  int* relbase  = grouped + N_EDGES;     // [NBKT*EB] 0.61 MB (dead after k_group)

  const bool use_h18 = ws_size >= WS_NEED;

  // d_out: x8 fp8 (lower quarter) + xb bf16 root (upper half); consumed by
  // fused1, then fused2 overwrites ALL of d_out.
  unsigned char* x8  = (unsigned char*)d_out;
  unsigned short* xb = (unsigned short*)d_out + (size_t)N_NODES * D;

  const int tiles = (N_NODES + 63) / 64;  // 1563

  k_bcount_cvt<<<EB, 256, 0, stream>>>(ei, relbase, x, x8, xb);
  k_scan_bkt<<<NBKT, 256, 0, stream>>>(relbase, bktsum);
  k_scan_start_cvtw<<<1, 512, 0, stream>>>(bktsum, bktstart,
                                           w1_l, w1_r, w2_l, w2_r, wb);
  k_group<<<EB, 256, 0, stream>>>(ei, relbase, bktstart, grouped);
  k_build<<<NBKT, 256, 0, stream>>>(grouped, bktstart, bktsum, deg, cursor, ssrc);

  if (use_h18) {
    sage_fused_mfma<true, 2><<<tiles, 256, 0, stream>>>(
        cursor, deg, ssrc, x8, xb, wb, wb + 4096, b1_l,
        bn1_g, bn1_b, bn1_m, bn1_v, h1, h18);
    sage_fused_mfma<true, 0><<<tiles, 256, 0, stream>>>(
        cursor, deg, ssrc, h18, h1, wb + 8192, wb + 12288, b2_l,
        bn2_g, bn2_b, bn2_m, bn2_v, d_out, nullptr);
  } else {
    sage_fused_mfma<true, 1><<<tiles, 256, 0, stream>>>(
        cursor, deg, ssrc, x8, xb, wb, wb + 4096, b1_l,
        bn1_g, bn1_b, bn1_m, bn1_v, h1, nullptr);
    sage_fused_mfma<false, 0><<<tiles, 256, 0, stream>>>(
        cursor, deg, ssrc, h1, h1, wb + 8192, wb + 12288, b2_l,
        bn2_g, bn2_b, bn2_m, bn2_v, d_out, nullptr);
  }
}

// Round 18
// 141.919 us; speedup vs baseline: 1.3649x; 1.0316x over previous
//
#include <hip/hip_runtime.h>
#include <hip/hip_bf16.h>
#include <hip/hip_fp8.h>

#define N_NODES 100000
#define N_EDGES 1600000
#define D 64
#define BN_EPS 1e-5f
#define NBKT 391   // buckets of 256 nodes
#define EPB 4096   // edges per block in pass A/B
#define EB 391     // ceil(N_EDGES/EPB)
#define AGS 68     // LDS agg row stride (shorts)
#define ICAP 48    // staged indices per node (P(deg>48) ~ 0 at Poisson(16))
#define ISTR 52    // idx_t row stride (ints)
#define WS_NEED 26437632ull

typedef unsigned short u16x8 __attribute__((ext_vector_type(8)));
typedef __bf16 bf16x8 __attribute__((ext_vector_type(8)));
typedef float f32x4 __attribute__((ext_vector_type(4)));
typedef float f32x2 __attribute__((ext_vector_type(2)));

static __device__ inline unsigned short f2bf_bits(float v) {
  __hip_bfloat16 h = __float2bfloat16(v);
  return *reinterpret_cast<unsigned short*>(&h);
}

// hardware fp8 e4m3 encode: 4 floats -> 4 bytes (RNE, saturating)
static __device__ inline unsigned int pk_fp8x4(float a, float b, float c, float d) {
  int p = __builtin_amdgcn_cvt_pk_fp8_f32(a, b, 0, false);
  p = __builtin_amdgcn_cvt_pk_fp8_f32(c, d, p, true);
  return (unsigned int)p;
}

// ---------------- CSR build (atomic-free at global scope) ----------------

__global__ __launch_bounds__(256) void k_bcount_cvt(
    const int* __restrict__ ei, int* __restrict__ relbase,
    const float* __restrict__ x, unsigned char* __restrict__ x8,
    unsigned short* __restrict__ xb) {
  __shared__ int h[NBKT];
  const int tid = threadIdx.x;
  for (int i = tid; i < NBKT; i += 256) h[i] = 0;
  __syncthreads();
#pragma unroll
  for (int k = 0; k < 4; ++k) {
    int e = blockIdx.x * EPB + k * 1024 + tid * 4;
    if (e < N_EDGES) {
      int4 d = *(const int4*)(ei + N_EDGES + e);
      atomicAdd(&h[d.x >> 8], 1);
      atomicAdd(&h[d.y >> 8], 1);
      atomicAdd(&h[d.z >> 8], 1);
      atomicAdd(&h[d.w >> 8], 1);
    }
  }
  // folded conversion: grid-stride over N*D/4 float4 chunks (HW fp8 encode)
  for (long i = (long)blockIdx.x * 256 + tid; i < (long)N_NODES * D / 4;
       i += (long)EB * 256) {
    float4 v = *(const float4*)(x + i * 4);
    *(unsigned int*)(x8 + i * 4) = pk_fp8x4(v.x, v.y, v.z, v.w);
    ushort4 u;
    u.x = f2bf_bits(v.x); u.y = f2bf_bits(v.y);
    u.z = f2bf_bits(v.z); u.w = f2bf_bits(v.w);
    *(ushort4*)(xb + i * 4) = u;
  }
  __syncthreads();
  for (int i = tid; i < NBKT; i += 256)
    relbase[i * EB + blockIdx.x] = h[i];  // bucket-major
}

__global__ __launch_bounds__(256) void k_scan_bkt(int* __restrict__ relbase,
                                                  int* __restrict__ bktsum) {
  __shared__ int sd[256];
  __shared__ int carry;
  const int i = blockIdx.x;
  const int tid = threadIdx.x;
  if (tid == 0) carry = 0;
  __syncthreads();
  int* p = relbase + i * EB;
  for (int c0 = 0; c0 < EB; c0 += 256) {
    int idx = c0 + tid;
    int v = (idx < EB) ? p[idx] : 0;
    sd[tid] = v;
    __syncthreads();
    for (int ofs = 1; ofs < 256; ofs <<= 1) {
      int t = (tid >= ofs) ? sd[tid - ofs] : 0;
      __syncthreads();
      sd[tid] += t;
      __syncthreads();
    }
    int excl = carry + sd[tid] - v;
    if (idx < EB) p[idx] = excl;
    __syncthreads();
    if (tid == 255) carry += sd[255];
    __syncthreads();
  }
  if (tid == 0) bktsum[i] = carry;
}

__global__ __launch_bounds__(512) void k_scan_start_cvtw(
    const int* __restrict__ bktsum, int* __restrict__ bktstart,
    const float* __restrict__ w0, const float* __restrict__ w1,
    const float* __restrict__ w2, const float* __restrict__ w3,
    unsigned short* __restrict__ wb) {
  __shared__ int sd[512];
  const int tid = threadIdx.x;
  int v = (tid < NBKT) ? bktsum[tid] : 0;
  sd[tid] = v;
  __syncthreads();
  for (int ofs = 1; ofs < 512; ofs <<= 1) {
    int t = (tid >= ofs) ? sd[tid - ofs] : 0;
    __syncthreads();
    sd[tid] += t;
    __syncthreads();
  }
  if (tid < NBKT) bktstart[tid] = sd[tid] - v;
  for (int i = tid; i < 4096; i += 512) {
    const float* src = (i < 1024) ? w0 : (i < 2048) ? w1 : (i < 3072) ? w2 : w3;
    int off = (i & 1023) * 4;
    float4 f = *(const float4*)(src + off);
    ushort4 u;
    u.x = f2bf_bits(f.x); u.y = f2bf_bits(f.y);
    u.z = f2bf_bits(f.z); u.w = f2bf_bits(f.w);
    *(ushort4*)(wb + (i >> 10) * 4096 + off) = u;
  }
}

__global__ __launch_bounds__(256) void k_group(const int* __restrict__ ei,
                                               const int* __restrict__ relbase,
                                               const int* __restrict__ bktstart,
                                               int* __restrict__ grouped) {
  __shared__ int cur[NBKT];
  const int tid = threadIdx.x;
  const int b = blockIdx.x;
  for (int i = tid; i < NBKT; i += 256)
    cur[i] = bktstart[i] + relbase[i * EB + b];
  __syncthreads();
#pragma unroll
  for (int k = 0; k < 4; ++k) {
    int e = b * EPB + k * 1024 + tid * 4;
    if (e < N_EDGES) {
      int4 s = *(const int4*)(ei + e);
      int4 d = *(const int4*)(ei + N_EDGES + e);
      int p;
      p = atomicAdd(&cur[d.x >> 8], 1); grouped[p] = s.x | ((d.x & 255) << 17);
      p = atomicAdd(&cur[d.y >> 8], 1); grouped[p] = s.y | ((d.y & 255) << 17);
      p = atomicAdd(&cur[d.z >> 8], 1); grouped[p] = s.z | ((d.z & 255) << 17);
      p = atomicAdd(&cur[d.w >> 8], 1); grouped[p] = s.w | ((d.w & 255) << 17);
    }
  }
}

// Pass C with src-quarter sub-ordering (round-15 proven).
__global__ __launch_bounds__(256) void k_build(const int* __restrict__ grouped,
                                               const int* __restrict__ bktstart,
                                               const int* __restrict__ bktsum,
                                               int* __restrict__ deg,
                                               int* __restrict__ cursor,
                                               int* __restrict__ ssrc) {
  __shared__ int cnt[1024];
  __shared__ int sd[256];
  __shared__ int carry;
  const int i = blockIdx.x;
  const int tid = threadIdx.x;
  const int gstart = bktstart[i];
  const int gnum = bktsum[i];
  for (int k = tid; k < 1024; k += 256) cnt[k] = 0;
  if (tid == 0) carry = 0;
  __syncthreads();
  for (int j = tid; j < gnum; j += 256) {
    int g = grouped[gstart + j];
    int key = ((((unsigned)g) >> 17) << 2) | ((g & 0x1ffff) >> 15);
    atomicAdd(&cnt[key], 1);
  }
  __syncthreads();
  int c0 = cnt[tid * 4 + 0], c1 = cnt[tid * 4 + 1];
  int c2 = cnt[tid * 4 + 2], c3 = cnt[tid * 4 + 3];
  __syncthreads();
  for (int c = 0; c < 4; ++c) {
    int idx = c * 256 + tid;
    int v = cnt[idx];
    sd[tid] = v;
    __syncthreads();
    for (int ofs = 1; ofs < 256; ofs <<= 1) {
      int t = (tid >= ofs) ? sd[tid - ofs] : 0;
      __syncthreads();
      sd[tid] += t;
      __syncthreads();
    }
    cnt[idx] = carry + sd[tid] - v;
    __syncthreads();
    if (tid == 255) carry += sd[255];
    __syncthreads();
  }
  int node = i * 256 + tid;
  if (node < N_NODES) {
    deg[node] = c0 + c1 + c2 + c3;
    cursor[node] = gstart + cnt[tid * 4];
  }
  __syncthreads();
  for (int j = tid; j < gnum; j += 256) {
    int g = grouped[gstart + j];
    int src = g & 0x1ffff;
    int key = ((((unsigned)g) >> 17) << 2) | (src >> 15);
    int p = gstart + atomicAdd(&cnt[key], 1);
    ssrc[p] = src;
  }
}

// ---------------- decode helpers ----------------

static __device__ inline void add_bf8(float* a, uint4 v) {
  unsigned int b;
  b = v.x << 16;         a[0] += *(float*)&b;
  b = v.x & 0xffff0000u; a[1] += *(float*)&b;
  b = v.y << 16;         a[2] += *(float*)&b;
  b = v.y & 0xffff0000u; a[3] += *(float*)&b;
  b = v.z << 16;         a[4] += *(float*)&b;
  b = v.z & 0xffff0000u; a[5] += *(float*)&b;
  b = v.w << 16;         a[6] += *(float*)&b;
  b = v.w & 0xffff0000u; a[7] += *(float*)&b;
}

// hardware fp8 e4m3 decode: uint2 = 8 bytes -> 8 floats accumulated
static __device__ inline void add_fp8x8(float* a, uint2 v) {
  f32x2 p0 = __builtin_amdgcn_cvt_pk_f32_fp8((int)v.x, false);
  f32x2 p1 = __builtin_amdgcn_cvt_pk_f32_fp8((int)v.x, true);
  f32x2 p2 = __builtin_amdgcn_cvt_pk_f32_fp8((int)v.y, false);
  f32x2 p3 = __builtin_amdgcn_cvt_pk_f32_fp8((int)v.y, true);
  a[0] += p0[0]; a[1] += p0[1]; a[2] += p1[0]; a[3] += p1[1];
  a[4] += p2[0]; a[5] += p2[1]; a[6] += p3[0]; a[7] += p3[1];
}

// ---------------- fused gather + MFMA GEMM + ELU + BN ----------------
// Phase 1: both passes' indices staged up front (one index round-trip for
// the whole block-tile); predicated full-width tail; HW fp8 decode.
// Phase 2: round-10/14 MFMA with pre-converted bf16 weights.
// OUT_MODE: 0 = f32 out; 1 = bf16 out; 2 = bf16 out + fp8 copy (out8).

template <bool G_FP8, int OUT_MODE>
__global__ __launch_bounds__(256) void sage_fused_mfma(
    const int* __restrict__ cursor, const int* __restrict__ deg_a,
    const int* __restrict__ ssrc,
    const void* __restrict__ gsrc,              // gather: fp8 or bf16 [N][D]
    const unsigned short* __restrict__ rootp,   // root rows: bf16 [N][D]
    const unsigned short* __restrict__ wbl,     // bf16 Wl [64][64]
    const unsigned short* __restrict__ wbr,     // bf16 Wr [64][64]
    const float* __restrict__ bl,
    const float* __restrict__ gamma, const float* __restrict__ beta,
    const float* __restrict__ mean, const float* __restrict__ var,
    void* __restrict__ out, unsigned char* __restrict__ out8) {
  __shared__ unsigned short agg_t[64 * AGS];  // bf16 agg, 8704 B
  __shared__ int idx_t[64 * ISTR];            // staged indices, 13312 B
  const int tid = threadIdx.x;
  const int base = blockIdx.x * 64;
  const int grp = tid >> 3;  // 8-lane group, 0..31
  const int q8 = tid & 7;    // 8-feature chunk / stage lane

  // ---- stage ALL indices for both passes up front (one round-trip) ----
  int stv[2], dgv[2], capv[2];
#pragma unroll
  for (int p = 0; p < 2; ++p) {
    int n = base + p * 32 + grp;
    if (n < N_NODES) {
      stv[p] = cursor[n];
      dgv[p] = deg_a[n];
    } else {
      stv[p] = 0;
      dgv[p] = 0;
    }
    capv[p] = dgv[p] < ICAP ? dgv[p] : ICAP;
    const int g0 = (p * 32 + grp) * ISTR;
#pragma unroll
    for (int j = 0; j < 6; ++j) {
      int jj = q8 + j * 8;
      if (jj < capv[p]) idx_t[g0 + jj] = ssrc[stv[p] + jj];
    }
  }

  // ---- phase 1: gather-aggregate into LDS (wave-synchronous idx reads) ----
  for (int p = 0; p < 2; ++p) {
    int r = p * 32 + grp;
    int n = base + r;
    float a[8] = {0.f, 0.f, 0.f, 0.f, 0.f, 0.f, 0.f, 0.f};
    if (n < N_NODES) {
      int st = stv[p], dg = dgv[p], cap = capv[p];
      const int g0 = r * ISTR;
      if constexpr (G_FP8) {
        const unsigned char* gs = (const unsigned char*)gsrc;
        for (int u = 0; u < cap; u += 8) {
          int rem = cap - u;  // 1..8
          int s0 = idx_t[g0 + u];
          int s1 = idx_t[g0 + u + (1 < rem ? 1 : 0)];
          int s2 = idx_t[g0 + u + (2 < rem ? 2 : 0)];
          int s3 = idx_t[g0 + u + (3 < rem ? 3 : 0)];
          int s4 = idx_t[g0 + u + (4 < rem ? 4 : 0)];
          int s5 = idx_t[g0 + u + (5 < rem ? 5 : 0)];
          int s6 = idx_t[g0 + u + (6 < rem ? 6 : 0)];
          int s7 = idx_t[g0 + u + (7 < rem ? 7 : 0)];
          uint2 v0 = *((const uint2*)(gs + (long)s0 * D) + q8);
          uint2 v1 = *((const uint2*)(gs + (long)s1 * D) + q8);
          uint2 v2 = *((const uint2*)(gs + (long)s2 * D) + q8);
          uint2 v3 = *((const uint2*)(gs + (long)s3 * D) + q8);
          uint2 v4 = *((const uint2*)(gs + (long)s4 * D) + q8);
          uint2 v5 = *((const uint2*)(gs + (long)s5 * D) + q8);
          uint2 v6 = *((const uint2*)(gs + (long)s6 * D) + q8);
          uint2 v7 = *((const uint2*)(gs + (long)s7 * D) + q8);
          v1.x = 1 < rem ? v1.x : 0u; v1.y = 1 < rem ? v1.y : 0u;
          v2.x = 2 < rem ? v2.x : 0u; v2.y = 2 < rem ? v2.y : 0u;
          v3.x = 3 < rem ? v3.x : 0u; v3.y = 3 < rem ? v3.y : 0u;
          v4.x = 4 < rem ? v4.x : 0u; v4.y = 4 < rem ? v4.y : 0u;
          v5.x = 5 < rem ? v5.x : 0u; v5.y = 5 < rem ? v5.y : 0u;
          v6.x = 6 < rem ? v6.x : 0u; v6.y = 6 < rem ? v6.y : 0u;
          v7.x = 7 < rem ? v7.x : 0u; v7.y = 7 < rem ? v7.y : 0u;
          add_fp8x8(a, v0); add_fp8x8(a, v1); add_fp8x8(a, v2); add_fp8x8(a, v3);
          add_fp8x8(a, v4); add_fp8x8(a, v5); add_fp8x8(a, v6); add_fp8x8(a, v7);
        }
        for (int u = cap; u < dg; ++u) {  // deg > ICAP fallback (rare)
          uint2 v = *((const uint2*)(gs + (long)ssrc[st + u] * D) + q8);
          add_fp8x8(a, v);
        }
      } else {
        const unsigned short* gs = (const unsigned short*)gsrc;
        for (int u = 0; u < cap; u += 8) {
          int rem = cap - u;
          int s0 = idx_t[g0 + u];
          int s1 = idx_t[g0 + u + (1 < rem ? 1 : 0)];
          int s2 = idx_t[g0 + u + (2 < rem ? 2 : 0)];
          int s3 = idx_t[g0 + u + (3 < rem ? 3 : 0)];
          int s4 = idx_t[g0 + u + (4 < rem ? 4 : 0)];
          int s5 = idx_t[g0 + u + (5 < rem ? 5 : 0)];
          int s6 = idx_t[g0 + u + (6 < rem ? 6 : 0)];
          int s7 = idx_t[g0 + u + (7 < rem ? 7 : 0)];
          uint4 v0 = *((const uint4*)(gs + (long)s0 * D) + q8);
          uint4 v1 = *((const uint4*)(gs + (long)s1 * D) + q8);
          uint4 v2 = *((const uint4*)(gs + (long)s2 * D) + q8);
          uint4 v3 = *((const uint4*)(gs + (long)s3 * D) + q8);
          uint4 v4 = *((const uint4*)(gs + (long)s4 * D) + q8);
          uint4 v5 = *((const uint4*)(gs + (long)s5 * D) + q8);
          uint4 v6 = *((const uint4*)(gs + (long)s6 * D) + q8);
          uint4 v7 = *((const uint4*)(gs + (long)s7 * D) + q8);
          if (1 >= rem) v1 = make_uint4(0, 0, 0, 0);
          if (2 >= rem) v2 = make_uint4(0, 0, 0, 0);
          if (3 >= rem) v3 = make_uint4(0, 0, 0, 0);
          if (4 >= rem) v4 = make_uint4(0, 0, 0, 0);
          if (5 >= rem) v5 = make_uint4(0, 0, 0, 0);
          if (6 >= rem) v6 = make_uint4(0, 0, 0, 0);
          if (7 >= rem) v7 = make_uint4(0, 0, 0, 0);
          add_bf8(a, v0); add_bf8(a, v1); add_bf8(a, v2); add_bf8(a, v3);
          add_bf8(a, v4); add_bf8(a, v5); add_bf8(a, v6); add_bf8(a, v7);
        }
        for (int u = cap; u < dg; ++u) {
          uint4 v = *((const uint4*)(gs + (long)ssrc[st + u] * D) + q8);
          add_bf8(a, v);
        }
      }
      float invd = 1.0f / fmaxf((float)dg, 1.0f);
#pragma unroll
      for (int j = 0; j < 8; ++j) a[j] *= invd;
    }
    ushort4 u0, u1;
    u0.x = f2bf_bits(a[0]); u0.y = f2bf_bits(a[1]);
    u0.z = f2bf_bits(a[2]); u0.w = f2bf_bits(a[3]);
    u1.x = f2bf_bits(a[4]); u1.y = f2bf_bits(a[5]);
    u1.z = f2bf_bits(a[6]); u1.w = f2bf_bits(a[7]);
    *(ushort4*)&agg_t[r * AGS + q8 * 8 + 0] = u0;
    *(ushort4*)&agg_t[r * AGS + q8 * 8 + 4] = u1;
  }
  __syncthreads();

  // ---- phase 2: MFMA, all operands bf16 direct loads (round-14 proven) ----
  const int lane = tid & 63;
  const int wv = tid >> 6;
  const int c16 = lane & 15;
  const int kg = lane >> 4;
  const int node0 = base + wv * 16;
  const int rloc = wv * 16 + c16;

  bf16x8 afr[4];
  afr[0] = __builtin_bit_cast(bf16x8, *(const u16x8*)&agg_t[rloc * AGS + kg * 8]);
  afr[1] = __builtin_bit_cast(bf16x8, *(const u16x8*)&agg_t[rloc * AGS + 32 + kg * 8]);
  long nrow = node0 + c16;
  long nclamp = (nrow < N_NODES) ? nrow : (N_NODES - 1);
  {
    const unsigned short* rp = rootp + nclamp * D;
    afr[2] = __builtin_bit_cast(bf16x8, *(const u16x8*)(rp + kg * 8));
    afr[3] = __builtin_bit_cast(bf16x8, *(const u16x8*)(rp + 32 + kg * 8));
  }

  f32x4 acc[4];
#pragma unroll
  for (int ot = 0; ot < 4; ++ot) acc[ot] = (f32x4){0.f, 0.f, 0.f, 0.f};
#pragma unroll
  for (int ot = 0; ot < 4; ++ot) {
    const long wrow = (long)(ot * 16 + c16) * 64;
    bf16x8 b0 = __builtin_bit_cast(bf16x8, *(const u16x8*)(wbl + wrow + kg * 8));
    bf16x8 b1 = __builtin_bit_cast(bf16x8, *(const u16x8*)(wbl + wrow + 32 + kg * 8));
    bf16x8 b2 = __builtin_bit_cast(bf16x8, *(const u16x8*)(wbr + wrow + kg * 8));
    bf16x8 b3 = __builtin_bit_cast(bf16x8, *(const u16x8*)(wbr + wrow + 32 + kg * 8));
    acc[ot] = __builtin_amdgcn_mfma_f32_16x16x32_bf16(afr[0], b0, acc[ot], 0, 0, 0);
    acc[ot] = __builtin_amdgcn_mfma_f32_16x16x32_bf16(afr[1], b1, acc[ot], 0, 0, 0);
    acc[ot] = __builtin_amdgcn_mfma_f32_16x16x32_bf16(afr[2], b2, acc[ot], 0, 0, 0);
    acc[ot] = __builtin_amdgcn_mfma_f32_16x16x32_bf16(afr[3], b3, acc[ot], 0, 0, 0);
  }

  // ---- epilogue ----
  float scv[4], shv[4], blv[4];
#pragma unroll
  for (int ot = 0; ot < 4; ++ot) {
    int ch = ot * 16 + c16;
    float sc = gamma[ch] * rsqrtf(var[ch] + BN_EPS);
    scv[ot] = sc;
    shv[ot] = beta[ch] - mean[ch] * sc;
    blv[ot] = bl[ch];
  }
#pragma unroll
  for (int r = 0; r < 4; ++r) {
    long node_out = node0 + kg * 4 + r;
    if (node_out < N_NODES) {
      float o[4];
#pragma unroll
      for (int ot = 0; ot < 4; ++ot) {
        float v = acc[ot][r] + blv[ot];
        v = v > 0.f ? v : expm1f(v);
        o[ot] = v * scv[ot] + shv[ot];
      }
      if constexpr (OUT_MODE == 0) {
#pragma unroll
        for (int ot = 0; ot < 4; ++ot)
          ((float*)out)[node_out * D + ot * 16 + c16] = o[ot];
      } else {
#pragma unroll
        for (int ot = 0; ot < 4; ++ot)
          ((unsigned short*)out)[node_out * D + ot * 16 + c16] = f2bf_bits(o[ot]);
        if constexpr (OUT_MODE == 2) {
          unsigned int pk = pk_fp8x4(o[0], o[1], o[2], o[3]);
          out8[node_out * D + 0 * 16 + c16] = pk & 0xff;
          out8[node_out * D + 1 * 16 + c16] = (pk >> 8) & 0xff;
          out8[node_out * D + 2 * 16 + c16] = (pk >> 16) & 0xff;
          out8[node_out * D + 3 * 16 + c16] = (pk >> 24) & 0xff;
        }
      }
    }
  }
}

// ---------------- launch ----------------

extern "C" void kernel_launch(void* const* d_in, const int* in_sizes, int n_in,
                              void* d_out, int out_size, void* d_ws, size_t ws_size,
                              hipStream_t stream) {
  const float* x     = (const float*)d_in[0];
  const int*   ei    = (const int*)d_in[1];
  const float* w1_l  = (const float*)d_in[2];
  const float* b1_l  = (const float*)d_in[3];
  const float* w1_r  = (const float*)d_in[4];
  const float* w2_l  = (const float*)d_in[5];
  const float* b2_l  = (const float*)d_in[6];
  const float* w2_r  = (const float*)d_in[7];
  const float* bn1_g = (const float*)d_in[8];
  const float* bn1_b = (const float*)d_in[9];
  const float* bn1_m = (const float*)d_in[10];
  const float* bn1_v = (const float*)d_in[11];
  const float* bn2_g = (const float*)d_in[12];
  const float* bn2_b = (const float*)d_in[13];
  const float* bn2_m = (const float*)d_in[14];
  const float* bn2_v = (const float*)d_in[15];

  // ws layout:
  int* deg      = (int*)d_ws;            // [100096]
  int* cursor   = deg + 100096;          // [100096]
  int* bktsum   = cursor + 100096;       // [512]
  int* bktstart = bktsum + 512;          // [512]
  int* ssrc     = bktstart + 512;        // [E]
  unsigned short* h1 = (unsigned short*)(ssrc + N_EDGES);  // bf16 [N*D], 12.8 MB
  unsigned short* wb = h1 + (size_t)N_NODES * D;           // bf16 weights, 32 KB
  unsigned char* h18 = (unsigned char*)(wb + 16384);       // fp8 [N*D], 6.4 MB
  int* grouped  = (int*)h1;              // [E] aliases h1 (dead after k_build)
  int* relbase  = grouped + N_EDGES;     // [NBKT*EB] (dead after k_group)

  const bool use_h18 = ws_size >= WS_NEED;

  unsigned char* x8  = (unsigned char*)d_out;
  unsigned short* xb = (unsigned short*)d_out + (size_t)N_NODES * D;

  const int tiles = (N_NODES + 63) / 64;  // 1563

  k_bcount_cvt<<<EB, 256, 0, stream>>>(ei, relbase, x, x8, xb);
  k_scan_bkt<<<NBKT, 256, 0, stream>>>(relbase, bktsum);
  k_scan_start_cvtw<<<1, 512, 0, stream>>>(bktsum, bktstart,
                                           w1_l, w1_r, w2_l, w2_r, wb);
  k_group<<<EB, 256, 0, stream>>>(ei, relbase, bktstart, grouped);
  k_build<<<NBKT, 256, 0, stream>>>(grouped, bktstart, bktsum, deg, cursor, ssrc);

  if (use_h18) {
    sage_fused_mfma<true, 2><<<tiles, 256, 0, stream>>>(
        cursor, deg, ssrc, x8, xb, wb, wb + 4096, b1_l,
        bn1_g, bn1_b, bn1_m, bn1_v, h1, h18);
    sage_fused_mfma<true, 0><<<tiles, 256, 0, stream>>>(
        cursor, deg, ssrc, h18, h1, wb + 8192, wb + 12288, b2_l,
        bn2_g, bn2_b, bn2_m, bn2_v, d_out, nullptr);
  } else {
    sage_fused_mfma<true, 1><<<tiles, 256, 0, stream>>>(
        cursor, deg, ssrc, x8, xb, wb, wb + 4096, b1_l,
        bn1_g, bn1_b, bn1_m, bn1_v, h1, nullptr);
    sage_fused_mfma<false, 0><<<tiles, 256, 0, stream>>>(
        cursor, deg, ssrc, h1, h1, wb + 8192, wb + 12288, b2_l,
        bn2_g, bn2_b, bn2_m, bn2_v, d_out, nullptr);
  }
}